// Round 12
// baseline (637.719 us; speedup 1.0000x reference)
//
#include <hip/hip_runtime.h>

#define NPTS 4096
#define KNN 20
#define CNT1f 655360.0f   // B*N*K
#define CNT3f 32768.0f    // B*N
#define BNEPS 1e-5f

// ---- workspace layout (float offsets into d_ws) ----
#define OFF_IDX   0
#define OFF_M     655360     // bf16[32768*128] = 2097152 floats -> ends 2752512
#define OFF_ES    655360     // 32 partials x 32 (27 used)  (alias, pre-c2apply)
#define OFF_G1P   656384     // 4*4096
#define OFF_S1P   672768     // 4*64
#define ZERO1_BEG 655360
#define ZERO1_CNT 17664
#define OFF_W2B   2752512    // bf16[8192]   = 4096 floats
#define OFF_W3B   2756608    // bf16[131072] = 65536 floats -> ends 2822144
#define OFF_XP    2822144    // float4[8*4096] = 131072 floats -> ends 2953216
#define OFF_G3P   2953216    // 2*16384
#define OFF_SM3P  2985984    // 2*128
#define OFF_GMAX  2986240    // 8*1024
#define OFF_Z4    2994432    // 8*512 (no zeroing needed: fc4 full-stores)
#define ZG3_BEG   2953216
#define ZG3_CNT   41216      // G3P + SM3P + GMAX
#define OFF_SC1   4849664
#define OFF_SH1   4849728
#define OFF_SC2   4849792
#define OFF_SH2   4849920
#define OFF_SC3   4850048
#define OFF_SH3   4851072

typedef float f32x4 __attribute__((ext_vector_type(4)));
typedef short s16x8 __attribute__((ext_vector_type(8)));

__device__ __forceinline__ unsigned short f2bf(float f) {   // RNE fp32->bf16
    unsigned u = __float_as_uint(f);
    return (unsigned short)((u + 0x7FFFu + ((u >> 16) & 1u)) >> 16);
}

// zero accum regions + bf16 weight convert + packed float4 point array
__global__ __launch_bounds__(256) void k_initprep(const float* __restrict__ x,
                                                  const float* __restrict__ w2,
                                                  const float* __restrict__ w3, float* W) {
    int i = blockIdx.x * 256 + threadIdx.x;   // grid 512 -> 131072 threads
    unsigned short* w2b = (unsigned short*)(W + OFF_W2B);
    unsigned short* w3b = (unsigned short*)(W + OFF_W3B);
    w3b[i] = f2bf(w3[i]);
    if (i < 8192) w2b[i] = f2bf(w2[i]);
    if (i < ZERO1_CNT) W[ZERO1_BEG + i] = 0.0f;
    if (i < ZG3_CNT) W[ZG3_BEG + i] = 0.0f;
    if (i < 32768) {
        int b = i >> 12, j = i & 4095;
        float4 p;
        p.x = x[b * 12288 + j];
        p.y = x[b * 12288 + 4096 + j];
        p.z = x[b * 12288 + 8192 + j];
        p.w = 0.f;
        ((float4*)(W + OFF_XP))[i] = p;
    }
}

// ---- wave-wide: find bin B containing the K-th smallest (1-indexed) in H ----
template <int PER>
__device__ __forceinline__ void wave_scan_find(const int* H, int K, int lane,
                                               int& B, int& below, int& hB) {
    int c[PER]; int s = 0;
    const int base = lane * PER;
#pragma unroll
    for (int p = 0; p < PER; ++p) { c[p] = H[base + p]; s += c[p]; }
    int pre = s;
#pragma unroll
    for (int off = 1; off < 64; off <<= 1) {
        int t = __shfl_up(pre, off, 64);
        if (lane >= off) pre += t;
    }
    int excl = pre - s;
    bool has = (excl < K) && (K <= excl + s);
    unsigned long long m = __ballot(has);
    int src = (int)(__ffsll((unsigned long long)m) - 1);
    int mb = 0, mbelow = 0, mh = 0;
    if (lane == src) {
        int cum = excl;
#pragma unroll
        for (int p = 0; p < PER; ++p) {
            if (cum < K && K <= cum + c[p]) { mb = base + p; mbelow = cum; mh = c[p]; break; }
            cum += c[p];
        }
    }
    B = __shfl(mb, src, 64);
    below = __shfl(mbelow, src, 64);
    hB = __shfl(mh, src, 64);
}

// -------- KNN radix-select: 2 waves per query, 32 keys/lane -----------------
// VGPR is the residency gate (R5/R9/R11: 80->33%, 120->22%, 136->11.5%).
// Halving cached keys to 32 targets VGPR<=64 (8-waves/SIMD cap) AND halves
// the per-wave critical path. Pair of waves shares a 512-bin histogram;
// all 3 radix levels (shifts 20/11/2, R7-validated) run unconditionally so
// block-wide barriers never diverge. Candidates from L2-resident packed
// float4 (R11). Downstream is order-invariant (top-20 SET).
__global__ __launch_bounds__(256) void k_knn(int* __restrict__ idx, float* W) {
    __shared__ int hist[2][512];                     // 4 KB
    __shared__ int outi[2][20];
    __shared__ int cnts[2][2];
    __shared__ unsigned int minsh[2][2];
    __shared__ float estat[27];
    const int tid = threadIdx.x;
    const int b = blockIdx.y;
    const float4* xb4 = ((const float4*)(W + OFF_XP)) + b * NPTS;
    if (tid < 27) estat[tid] = 0.f;
    if (tid < 4) cnts[tid >> 1][tid & 1] = 0;
    const int wv = tid >> 6, lane = tid & 63;
    const int pair = wv >> 1, half = wv & 1;
    const int tid128 = tid & 127;
    const int q = blockIdx.x * 2 + pair;
    const float4 qp = xb4[q];
    int* H = hist[pair];
#pragma unroll
    for (int p = 0; p < 4; ++p) H[tid128 * 4 + p] = 0;
    unsigned int key[32];
    unsigned int mymin = 0xFFFFFFFFu;
#pragma unroll
    for (int it = 0; it < 32; ++it) {
        int j = it * 128 + tid128;
        float4 pp = xb4[j];
        float dx = pp.x - qp.x, dy = pp.y - qp.y, dz = pp.z - qp.z;
        float d = fmaf(dx, dx, fmaf(dy, dy, dz * dz));
        unsigned int u = (j == q) ? 0xFFFFFFFFu : __float_as_uint(d);
        key[it] = u;
        mymin = mymin < u ? mymin : u;
    }
#pragma unroll
    for (int off = 32; off; off >>= 1) {
        unsigned int o = (unsigned int)__shfl_xor((int)mymin, off);
        mymin = mymin < o ? mymin : o;
    }
    if (lane == 0) minsh[pair][half] = mymin;
    __syncthreads();   // minsh + H zero + cnts/estat visible
    const unsigned int base = minsh[pair][0] < minsh[pair][1] ? minsh[pair][0] : minsh[pair][1];
    // ---- level 0: bins (t-base)>>20, clamped ----
#pragma unroll
    for (int it = 0; it < 32; ++it) {
        unsigned int t9 = key[it] - base;
        unsigned int bin = t9 >> 20; if (bin > 511u) bin = 511u;
        atomicAdd(&H[bin], 1);
    }
    __syncthreads();
    int B, below, hB;
    wave_scan_find<8>(H, KNN - 1, lane, B, below, hB);
    unsigned int P = (unsigned int)B;
    int rem = (KNN - 1) - below;
    __syncthreads();   // scans done reading H
    // ---- level 1: among prefix==P, bins (t>>11)&511 ----
#pragma unroll
    for (int p = 0; p < 4; ++p) H[tid128 * 4 + p] = 0;
    __syncthreads();
#pragma unroll
    for (int it = 0; it < 32; ++it) {
        unsigned int t9 = key[it] - base;
        unsigned int b0 = t9 >> 20; if (b0 > 511u) b0 = 511u;
        if (b0 == P) atomicAdd(&H[(t9 >> 11) & 511], 1);
    }
    __syncthreads();
    wave_scan_find<8>(H, rem, lane, B, below, hB);
    P = (P << 9) | (unsigned int)B;
    rem -= below;
    __syncthreads();
    // ---- level 2: among prefix==P, bins (t>>2)&511 ----
#pragma unroll
    for (int p = 0; p < 4; ++p) H[tid128 * 4 + p] = 0;
    __syncthreads();
#pragma unroll
    for (int it = 0; it < 32; ++it) {
        unsigned int t9 = key[it] - base;
        if ((t9 >> 11) == P) atomicAdd(&H[(t9 >> 2) & 511], 1);
    }
    __syncthreads();
    wave_scan_find<8>(H, rem, lane, B, below, hB);
    P = (P << 9) | (unsigned int)B;
    rem -= below;
    // ---- compact: v < P taken; v == P first `rem` taken (19 + self) ----
    int* OC = cnts[pair];
#pragma unroll
    for (int it = 0; it < 32; ++it) {
        unsigned int v = (key[it] - base) >> 2;
        if (v <= P) {
            bool take = v < P;
            if (!take) { int e = atomicAdd(&OC[1], 1); take = (e < rem); }
            if (take) { int pos = atomicAdd(&OC[0], 1); outi[pair][pos] = it * 128 + tid128; }
        }
    }
    if (half == 0 && lane == 0) outi[pair][KNN - 1] = q;
    __syncthreads();
    const int obase = (b * NPTS + q) * KNN;
    if (half == 0 && lane < KNN) idx[obase + lane] = outi[pair][lane];
    // fused edge moments for bn1 (half==0 wave of each pair, lanes 0..19)
    float st[27];
#pragma unroll
    for (int v = 0; v < 27; ++v) st[v] = 0.f;
    if (half == 0 && lane < KNN) {
        int j = outi[pair][lane];
        float4 np = xb4[j];
        float e[6];
        e[0] = qp.x; e[1] = qp.y; e[2] = qp.z;
        e[3] = np.x - qp.x; e[4] = np.y - qp.y; e[5] = np.z - qp.z;
        int id = 6;
#pragma unroll
        for (int i = 0; i < 6; ++i) {
            st[i] = e[i];
#pragma unroll
            for (int jj = i; jj < 6; ++jj) { st[id] = e[i] * e[jj]; id++; }
        }
    }
    if (half == 0) {
#pragma unroll
        for (int v = 0; v < 27; ++v) {
            float s = st[v];
            s += __shfl_xor(s, 32); s += __shfl_xor(s, 16); s += __shfl_xor(s, 8);
            s += __shfl_xor(s, 4);  s += __shfl_xor(s, 2);  s += __shfl_xor(s, 1);
            st[v] = s;
        }
        if (lane == 0) {
#pragma unroll
            for (int v = 0; v < 27; ++v) atomicAdd(&estat[v], st[v]);
        }
    }
    __syncthreads();
    if (tid < 27) atomicAdd(&W[OFF_ES + (blockIdx.x & 31) * 32 + tid], estat[tid]);
}

// bn1 affine from edge moments
__global__ void k_fin1(const float* __restrict__ w1, const float* __restrict__ g1,
                       const float* __restrict__ b1, float* W) {
    __shared__ float es[27];
    const int c = threadIdx.x;
    if (c < 27) {
        float s = 0.f;
        for (int p = 0; p < 32; ++p) s += W[OFF_ES + p * 32 + c];
        es[c] = s;
    }
    __syncthreads();
    float wr[6];
#pragma unroll
    for (int i = 0; i < 6; ++i) wr[i] = w1[c * 6 + i];
    float m = 0.f;
#pragma unroll
    for (int i = 0; i < 6; ++i) m += wr[i] * es[i];
    m *= (1.f / CNT1f);
    float qv = 0.f;
    int id = 6;
#pragma unroll
    for (int i = 0; i < 6; ++i)
#pragma unroll
        for (int jj = 0; jj < 6; ++jj)
            if (jj >= i) { qv += (jj == i ? 1.f : 2.f) * wr[i] * wr[jj] * es[id]; id++; }
    qv *= (1.f / CNT1f);
    float var = qv - m * m;
    float sc = g1[c] * rsqrtf(var + BNEPS);
    W[OFF_SC1 + c] = sc;
    W[OFF_SH1 + c] = b1[c] - m * sc;
}

// -------- gram1 (MFMA): G1 = Sum(h1 h1^T), S1 via appended ones-row ---------
__global__ __launch_bounds__(256) void k_gram1(const int* __restrict__ idx,
                                               const float* __restrict__ w1, float* W) {
    __shared__ unsigned short h1t[80 * 136];   // 21760 B
    __shared__ float eds[128 * 6];
    __shared__ float w1s[64 * 6];
    __shared__ float sc1s[64], sh1s[64];
    const int t = threadIdx.x;
    const int b = blockIdx.x >> 6;                 // 64 blocks per batch
    const int ebase_b = (blockIdx.x & 63) * 1280;  // edges within batch
    const float4* xpb = ((const float4*)(W + OFF_XP)) + b * NPTS;
    if (t < 384) w1s[t] = w1[t];
    if (t < 64) { sc1s[t] = W[OFF_SC1 + t]; sh1s[t] = W[OFF_SH1 + t]; }
    for (int i = t; i < 2048; i += 256) {          // rows 64..79
        int rr = i >> 7, e = i & 127;
        h1t[(64 + rr) * 136 + e] = (rr == 0) ? (unsigned short)0x3F80 : (unsigned short)0;
    }
    const int w = t >> 6, lane = t & 63, n16 = lane & 15, quad = lane >> 4;
    f32x4 acc[5];
#pragma unroll
    for (int j = 0; j < 5; ++j) acc[j] = (f32x4){0.f, 0.f, 0.f, 0.f};
    for (int ck = 0; ck < 10; ++ck) {
        __syncthreads();
        if (t < 128) {   // stage 128 edges
            int e_l = ebase_b + ck * 128 + t;
            int q = e_l / KNN;
            int jn = idx[b * (NPTS * KNN) + e_l];
            float4 c = xpb[q];
            float4 n = xpb[jn];
            float* E = &eds[t * 6];
            E[0] = c.x; E[1] = c.y; E[2] = c.z;
            E[3] = n.x - c.x; E[4] = n.y - c.y; E[5] = n.z - c.z;
        }
        __syncthreads();
        {   // h1 rows 0..63
            const int e128 = t & 127, half = t >> 7;
            float e0 = eds[e128 * 6 + 0], e1 = eds[e128 * 6 + 1], e2 = eds[e128 * 6 + 2];
            float e3 = eds[e128 * 6 + 3], e4 = eds[e128 * 6 + 4], e5 = eds[e128 * 6 + 5];
#pragma unroll 4
            for (int cc = 0; cc < 32; ++cc) {
                int c = half * 32 + cc;
                const float* wr = &w1s[c * 6];
                float z = wr[0] * e0 + wr[1] * e1 + wr[2] * e2 + wr[3] * e3 + wr[4] * e4 + wr[5] * e5;
                float h = sc1s[c] * z + sh1s[c];
                h1t[c * 136 + e128] = f2bf(h > 0.f ? h : 0.f);
            }
        }
        __syncthreads();
#pragma unroll
        for (int ks = 0; ks < 4; ++ks) {
            s16x8 Af = *(const s16x8*)&h1t[(w * 16 + n16) * 136 + ks * 32 + quad * 8];
#pragma unroll
            for (int jt = 0; jt < 5; ++jt) {
                s16x8 Bf = *(const s16x8*)&h1t[(jt * 16 + n16) * 136 + ks * 32 + quad * 8];
                acc[jt] = __builtin_amdgcn_mfma_f32_16x16x32_bf16(Af, Bf, acc[jt], 0, 0, 0);
            }
        }
    }
    const int part = blockIdx.x & 3;
    const int gi = w * 16 + quad * 4;
#pragma unroll
    for (int jt = 0; jt < 4; ++jt)
#pragma unroll
        for (int r = 0; r < 4; ++r)
            atomicAdd(&W[OFF_G1P + part * 4096 + (gi + r) * 64 + jt * 16 + n16], acc[jt][r]);
    if (n16 == 0) {
#pragma unroll
        for (int r = 0; r < 4; ++r)
            atomicAdd(&W[OFF_S1P + part * 64 + gi + r], acc[4][r]);
    }
}

// bn2 affine from Gram
__global__ __launch_bounds__(256) void k_fin2(const float* __restrict__ w2, const float* __restrict__ g2,
                                              const float* __restrict__ b2, float* W) {
    __shared__ float Gs[4096];
    __shared__ float s1s[64];
    __shared__ float w2s[128 * 65];
    const int t = threadIdx.x;
    for (int i = t; i < 4096; i += 256)
        Gs[i] = W[OFF_G1P + i] + W[OFF_G1P + 4096 + i] + W[OFF_G1P + 8192 + i] + W[OFF_G1P + 12288 + i];
    if (t < 64) s1s[t] = W[OFF_S1P + t] + W[OFF_S1P + 64 + t] + W[OFF_S1P + 128 + t] + W[OFF_S1P + 192 + t];
    for (int i = t; i < 8192; i += 256) w2s[(i >> 6) * 65 + (i & 63)] = w2[i];
    __syncthreads();
    const int c = t >> 1, half = t & 1;
    float acc = 0.f;
    for (int ii = 0; ii < 32; ++ii) {
        int i = 32 * half + ii;
        float wi = w2s[c * 65 + i];
        float inner = 0.f;
        for (int j = 0; j < 64; ++j) inner += Gs[i * 64 + j] * w2s[c * 65 + j];
        acc += wi * inner;
    }
    acc += __shfl_xor(acc, 1);
    if (half == 0) {
        float ms = 0.f;
        for (int j = 0; j < 64; ++j) ms += w2s[c * 65 + j] * s1s[j];
        float mean = ms * (1.f / CNT1f);
        float var = acc * (1.f / CNT1f) - mean * mean;
        float sc = g2[c] * rsqrtf(var + BNEPS);
        W[OFF_SC2 + c] = sc;
        W[OFF_SH2 + c] = b2[c] - mean * sc;
    }
}

// -------- c2apply (MFMA): conv1+bn1+relu -> conv2 -> bn2+relu -> maxK -> M --
__global__ __launch_bounds__(256) void k_c2apply(const int* __restrict__ idx,
                                                 const float* __restrict__ w1, float* W) {
    __shared__ unsigned short h1b[256 * 72];   // [row=q*32+kk][k=64 chans of h1]
    __shared__ float eds[160 * 6];
    const int t = threadIdx.x;
    const int b = blockIdx.y, q0 = blockIdx.x * 8;
    const float4* xpb = ((const float4*)(W + OFF_XP)) + b * NPTS;
    const int ebase = (b * NPTS + q0) * KNN;
    const unsigned short* w2b = (const unsigned short*)(W + OFF_W2B);
    if (t < 160) {
        int q = q0 + t / KNN;
        int jn = idx[ebase + t];
        float4 c = xpb[q];
        float4 n = xpb[jn];
        float* E = &eds[t * 6];
        E[0] = c.x; E[1] = c.y; E[2] = c.z;
        E[3] = n.x - c.x; E[4] = n.y - c.y; E[5] = n.z - c.z;
    }
    __syncthreads();
    {   // h1: thread (chan j64, grp of 2 queries); pad rows 20..31 with zeros
        const int j64 = t & 63, grp = t >> 6;
        float wr[6];
#pragma unroll
        for (int i = 0; i < 6; ++i) wr[i] = w1[j64 * 6 + i];
        const float sc = W[OFF_SC1 + j64], sh = W[OFF_SH1 + j64];
        for (int qq = grp * 2; qq < grp * 2 + 2; ++qq) {
#pragma unroll 4
            for (int kk = 0; kk < 32; ++kk) {
                float v = 0.f;
                if (kk < 20) {
                    const float* E = &eds[(qq * 20 + kk) * 6];
                    float z = wr[0] * E[0] + wr[1] * E[1] + wr[2] * E[2] + wr[3] * E[3] + wr[4] * E[4] + wr[5] * E[5];
                    float h = sc * z + sh;
                    v = h > 0.f ? h : 0.f;
                }
                h1b[(qq * 32 + kk) * 72 + j64] = f2bf(v);
            }
        }
    }
    __syncthreads();
    const int w = t >> 6, lane = t & 63, n16 = lane & 15, quad = lane >> 4;
    unsigned short* Mb = (unsigned short*)(W + OFF_M);
#pragma unroll
    for (int nt_i = 0; nt_i < 2; ++nt_i) {
        const int nt = 2 * w + nt_i;
        const int chan = nt * 16 + n16;
        const float sc2 = W[OFF_SC2 + chan], sh2 = W[OFF_SH2 + chan];
        s16x8 Bf0 = *(const s16x8*)&w2b[chan * 64 + quad * 8];
        s16x8 Bf1 = *(const s16x8*)&w2b[chan * 64 + 32 + quad * 8];
#pragma unroll
        for (int q = 0; q < 8; ++q) {
            f32x4 accA = (f32x4){0.f, 0.f, 0.f, 0.f};
            f32x4 accB = (f32x4){0.f, 0.f, 0.f, 0.f};
            s16x8 a0 = *(const s16x8*)&h1b[(q * 32 + n16) * 72 + quad * 8];
            s16x8 a1 = *(const s16x8*)&h1b[(q * 32 + 16 + n16) * 72 + quad * 8];
            accA = __builtin_amdgcn_mfma_f32_16x16x32_bf16(a0, Bf0, accA, 0, 0, 0);
            accB = __builtin_amdgcn_mfma_f32_16x16x32_bf16(a1, Bf0, accB, 0, 0, 0);
            a0 = *(const s16x8*)&h1b[(q * 32 + n16) * 72 + 32 + quad * 8];
            a1 = *(const s16x8*)&h1b[(q * 32 + 16 + n16) * 72 + 32 + quad * 8];
            accA = __builtin_amdgcn_mfma_f32_16x16x32_bf16(a0, Bf1, accA, 0, 0, 0);
            accB = __builtin_amdgcn_mfma_f32_16x16x32_bf16(a1, Bf1, accB, 0, 0, 0);
            float mx = 0.f;
#pragma unroll
            for (int r = 0; r < 4; ++r) {
                float h = sc2 * accA[r] + sh2;
                mx = fmaxf(mx, h > 0.f ? h : 0.f);
            }
            if (quad == 0) {   // kk = 16..19 valid only in quad 0
#pragma unroll
                for (int r = 0; r < 4; ++r) {
                    float h = sc2 * accB[r] + sh2;
                    mx = fmaxf(mx, h > 0.f ? h : 0.f);
                }
            }
            mx = fmaxf(mx, __shfl_xor(mx, 16));
            mx = fmaxf(mx, __shfl_xor(mx, 32));
            if (quad == 0)
                Mb[(b * NPTS + q0 + q) * 128 + chan] = f2bf(mx);
        }
    }
}

// -------- gram3 (MFMA): G3 = M^T M via transposed bf16 LDS tile -------------
__global__ __launch_bounds__(256) void k_gram3(float* W) {
    __shared__ unsigned short Mt[128 * 72];    // [chan][e], stride 72
    const int t = threadIdx.x;
    const int w = t >> 6, lane = t & 63, n16 = lane & 15, quad = lane >> 4;
    const int r0 = blockIdx.x * 512;
    const unsigned int* Msrc = (const unsigned int*)(W + OFF_M);
    const int nA = 8 - w;
    f32x4 acc[9];
#pragma unroll
    for (int j = 0; j < 9; ++j) acc[j] = (f32x4){0.f, 0.f, 0.f, 0.f};
    float smacc = 0.f;
    for (int ch = 0; ch < 8; ++ch) {
        __syncthreads();
        for (int i = t; i < 4096; i += 256) {   // stage 64 rows transposed
            int row = i >> 6, c2 = i & 63;
            unsigned int v = Msrc[(r0 + ch * 64 + row) * 64 + c2];
            Mt[(2 * c2) * 72 + row]     = (unsigned short)(v & 0xFFFFu);
            Mt[(2 * c2 + 1) * 72 + row] = (unsigned short)(v >> 16);
        }
        __syncthreads();
#pragma unroll
        for (int j = 0; j < 9; ++j) {
            int ti = (j < nA) ? w : (7 - w);
            int tj = (j < nA) ? (w + j) : (j - nA + 7 - w);
#pragma unroll
            for (int ks = 0; ks < 2; ++ks) {
                s16x8 Af = *(const s16x8*)&Mt[(ti * 16 + n16) * 72 + ks * 32 + quad * 8];
                s16x8 Bf = *(const s16x8*)&Mt[(tj * 16 + n16) * 72 + ks * 32 + quad * 8];
                acc[j] = __builtin_amdgcn_mfma_f32_16x16x32_bf16(Af, Bf, acc[j], 0, 0, 0);
            }
        }
        if (t < 128) {
            float s = 0.f;
            for (int e = 0; e < 64; ++e)
                s += __uint_as_float((unsigned int)Mt[t * 72 + e] << 16);
            smacc += s;
        }
    }
    const int part = blockIdx.x & 1;
    float* Gp = &W[OFF_G3P + part * 16384];
#pragma unroll
    for (int j = 0; j < 9; ++j) {
        int ti = (j < nA) ? w : (7 - w);
        int tj = (j < nA) ? (w + j) : (j - nA + 7 - w);
#pragma unroll
        for (int r = 0; r < 4; ++r)
            atomicAdd(&Gp[(ti * 16 + quad * 4 + r) * 128 + tj * 16 + n16], acc[j][r]);
    }
    if (t < 128) atomicAdd(&W[OFF_SM3P + part * 128 + t], smacc);
}

// bn3 affine: 16 channels per block; mirror lower triangle from upper tiles
__global__ __launch_bounds__(256) void k_fin3(const float* __restrict__ w3, const float* __restrict__ g3,
                                              const float* __restrict__ b3, float* W) {
    __shared__ float G3s[128 * 129];
    __shared__ float w3s[16 * 132];
    __shared__ float sm3[128];
    __shared__ float red[256];
    __shared__ float mred[16];
    const int t = threadIdx.x;
    const int c0 = blockIdx.x * 16;
    for (int i = t; i < 16384; i += 256) {
        int row = i >> 7, col = i & 127;
        int src = ((row >> 4) <= (col >> 4)) ? (row * 128 + col) : (col * 128 + row);
        G3s[row * 129 + col] = W[OFF_G3P + src] + W[OFF_G3P + 16384 + src];
    }
    for (int i = t; i < 2048; i += 256)
        w3s[(i >> 7) * 132 + (i & 127)] = w3[(c0 + (i >> 7)) * 128 + (i & 127)];
    if (t < 128) sm3[t] = W[OFF_SM3P + t] + W[OFF_SM3P + 128 + t];
    __syncthreads();
    const int cl = t >> 4, seg = t & 15;
    float acc = 0.f;
    for (int ii = 0; ii < 8; ++ii) {
        int i = 8 * seg + ii;
        float wi = w3s[cl * 132 + i];
        float inner = 0.f;
        for (int j = 0; j < 128; ++j) inner += G3s[i * 129 + j] * w3s[cl * 132 + j];
        acc += wi * inner;
    }
    red[t] = acc;
    if (seg == 0) {
        float ms = 0.f;
        for (int j = 0; j < 128; ++j) ms += w3s[cl * 132 + j] * sm3[j];
        mred[cl] = ms;
    }
    __syncthreads();
    if (t < 16) {
        float s = 0.f;
#pragma unroll
        for (int k = 0; k < 16; ++k) s += red[t * 16 + k];
        float mean = mred[t] * (1.f / CNT3f);
        float var = s * (1.f / CNT3f) - mean * mean;
        float sc = g3[c0 + t] * rsqrtf(var + BNEPS);
        W[OFF_SC3 + c0 + t] = sc;
        W[OFF_SH3 + c0 + t] = b3[c0 + t] - mean * sc;
    }
}

// -------- conv3 (MFMA): z3 = M @ w3^T, bn3+relu, max over rows -> GMAX ------
__global__ __launch_bounds__(256) void k_conv3(float* W) {
    __shared__ unsigned short Mt[64 * 136];     // 64 rows x K=128
    const int t = threadIdx.x;
    const int p0 = blockIdx.x * 64, c0g = blockIdx.y * 128;
    const unsigned int* Msrc = (const unsigned int*)(W + OFF_M);
    const unsigned short* w3b = (const unsigned short*)(W + OFF_W3B);
    for (int i = t; i < 4096; i += 256) {
        int row = i >> 6, c2 = i & 63;
        *(unsigned int*)&Mt[row * 136 + 2 * c2] = Msrc[(p0 + row) * 64 + c2];
    }
    __syncthreads();
    const int w = t >> 6, lane = t & 63, n16 = lane & 15, quad = lane >> 4;
    const int bbatch = p0 >> 12;
#pragma unroll
    for (int nt_i = 0; nt_i < 2; ++nt_i) {
        const int nt = 2 * w + nt_i;
        const int chan = c0g + nt * 16 + n16;
        const float sc3 = W[OFF_SC3 + chan], sh3 = W[OFF_SH3 + chan];
        s16x8 Bf[4];
#pragma unroll
        for (int ks = 0; ks < 4; ++ks)
            Bf[ks] = *(const s16x8*)&w3b[chan * 128 + ks * 32 + quad * 8];
        float mx = 0.f;
#pragma unroll
        for (int mt = 0; mt < 4; ++mt) {
            f32x4 acc = (f32x4){0.f, 0.f, 0.f, 0.f};
#pragma unroll
            for (int ks = 0; ks < 4; ++ks) {
                s16x8 Af = *(const s16x8*)&Mt[(mt * 16 + n16) * 136 + ks * 32 + quad * 8];
                acc = __builtin_amdgcn_mfma_f32_16x16x32_bf16(Af, Bf[ks], acc, 0, 0, 0);
            }
#pragma unroll
            for (int r = 0; r < 4; ++r) {
                float h = sc3 * acc[r] + sh3;
                mx = fmaxf(mx, h > 0.f ? h : 0.f);
            }
        }
        mx = fmaxf(mx, __shfl_xor(mx, 16));
        mx = fmaxf(mx, __shfl_xor(mx, 32));
        if (quad == 0)
            atomicMax((unsigned int*)&W[OFF_GMAX + bbatch * 1024 + chan], __float_as_uint(mx));
    }
}

// -------- z4 = gmax(8x1024) @ w4^T(512x1024) --------------------------------
__global__ __launch_bounds__(256) void k_fc4(const float* __restrict__ w4, float* W) {
    __shared__ float red[256];
    const int t = threadIdx.x;
    const int oidx = t >> 3, s = t & 7;
    const int cc = oidx >> 3, b = oidx & 7;
    const int c = blockIdx.x * 4 + cc;
    const float* g = &W[OFF_GMAX];
    const float* wr = &w4[c * 1024 + s * 128];
    const float* gr = &g[b * 1024 + s * 128];
    float p = 0.f;
    for (int j = 0; j < 128; ++j) p += wr[j] * gr[j];
    red[t] = p;
    __syncthreads();
    if (t < 32) {
        float tot = 0.f;
        for (int k = 0; k < 8; ++k) tot += red[t * 8 + k];
        W[OFF_Z4 + (t & 7) * 512 + blockIdx.x * 4 + (t >> 3)] = tot;
    }
}

// -------- tail: bn4+relu, fc5, bn5+relu, final linear + eye -----------------
__global__ __launch_bounds__(512) void k_tail(const float* __restrict__ g4, const float* __restrict__ b4,
                                              const float* __restrict__ w5, const float* __restrict__ g5,
                                              const float* __restrict__ b5, const float* __restrict__ wl,
                                              const float* __restrict__ bl, float* W, float* __restrict__ out) {
    __shared__ float h4L[8 * 512];
    __shared__ float w5s[2 * 256 * 9];
    __shared__ float zp[2 * 2048];
    const int t = threadIdx.x;
    {
        float v[8]; float s = 0.f, q = 0.f;
#pragma unroll
        for (int b = 0; b < 8; ++b) { v[b] = W[OFF_Z4 + b * 512 + t]; s += v[b]; q += v[b] * v[b]; }
        float mean = s * 0.125f;
        float var = q * 0.125f - mean * mean;
        float sc = g4[t] * rsqrtf(var + BNEPS);
        float sh = b4[t] - mean * sc;
#pragma unroll
        for (int b = 0; b < 8; ++b) {
            float h = sc * v[b] + sh;
            h4L[b * 512 + t] = h > 0.f ? h : 0.f;
        }
    }
    const int c5 = t & 255, half = t >> 8;
    float acc[8];
#pragma unroll
    for (int b = 0; b < 8; ++b) acc[b] = 0.f;
    for (int jt = 0; jt < 32; ++jt) {
        __syncthreads();
        for (int i = t; i < 4096; i += 512) {
            int h = i >> 11, rem = i & 2047;
            int ci = rem >> 3, jj = rem & 7;
            w5s[h * 2304 + ci * 9 + jj] = w5[ci * 512 + h * 256 + jt * 8 + jj];
        }
        __syncthreads();
#pragma unroll
        for (int jj = 0; jj < 8; ++jj) {
            float wv = w5s[half * 2304 + c5 * 9 + jj];
            int jg = half * 256 + jt * 8 + jj;
#pragma unroll
            for (int b = 0; b < 8; ++b) acc[b] += wv * h4L[b * 512 + jg];
        }
    }
#pragma unroll
    for (int b = 0; b < 8; ++b) zp[half * 2048 + b * 256 + c5] = acc[b];
    __syncthreads();
    if (t < 256) {
        float v[8], s = 0.f, q = 0.f;
#pragma unroll
        for (int b = 0; b < 8; ++b) {
            v[b] = zp[b * 256 + t] + zp[2048 + b * 256 + t];
            s += v[b]; q += v[b] * v[b];
        }
        float mean = s * 0.125f, var = q * 0.125f - mean * mean;
        float sc = g5[t] * rsqrtf(var + BNEPS), sh = b5[t] - mean * sc;
#pragma unroll
        for (int b = 0; b < 8; ++b) { float h = sc * v[b] + sh; zp[b * 256 + t] = h > 0.f ? h : 0.f; }
    }
    __syncthreads();
    if (t < 72) {
        int b = t / 9, r = t % 9;
        float a = bl[r] + ((r == 0 || r == 4 || r == 8) ? 1.f : 0.f);
        for (int j = 0; j < 256; ++j) a += wl[r * 256 + j] * zp[b * 256 + j];
        out[b * 9 + r] = a;
    }
}

extern "C" void kernel_launch(void* const* d_in, const int* in_sizes, int n_in,
                              void* d_out, int out_size, void* d_ws, size_t ws_size,
                              hipStream_t stream) {
    const float* x  = (const float*)d_in[0];
    const float* w1 = (const float*)d_in[1];
    const float* g1 = (const float*)d_in[2];
    const float* b1 = (const float*)d_in[3];
    const float* w2 = (const float*)d_in[4];
    const float* g2 = (const float*)d_in[5];
    const float* b2 = (const float*)d_in[6];
    const float* w3 = (const float*)d_in[7];
    const float* g3 = (const float*)d_in[8];
    const float* b3 = (const float*)d_in[9];
    const float* w4 = (const float*)d_in[10];
    const float* g4 = (const float*)d_in[11];
    const float* b4 = (const float*)d_in[12];
    const float* w5 = (const float*)d_in[13];
    const float* g5 = (const float*)d_in[14];
    const float* b5 = (const float*)d_in[15];
    const float* wl = (const float*)d_in[16];
    const float* bl = (const float*)d_in[17];
    float* W = (float*)d_ws;
    int* idx = (int*)d_ws;
    float* out = (float*)d_out;

    k_initprep<<<dim3(512), dim3(256), 0, stream>>>(x, w2, w3, W);
    k_knn<<<dim3(2048, 8), dim3(256), 0, stream>>>(idx, W);
    k_fin1<<<dim3(1), dim3(64), 0, stream>>>(w1, g1, b1, W);
    k_gram1<<<dim3(512), dim3(256), 0, stream>>>(idx, w1, W);
    k_fin2<<<dim3(1), dim3(256), 0, stream>>>(w2, g2, b2, W);
    k_c2apply<<<dim3(512, 8), dim3(256), 0, stream>>>(idx, w1, W);
    k_gram3<<<dim3(64), dim3(256), 0, stream>>>(W);
    k_fin3<<<dim3(64), dim3(256), 0, stream>>>(w3, g3, b3, W);
    k_conv3<<<dim3(512, 8), dim3(256), 0, stream>>>(W);
    k_fc4<<<dim3(128), dim3(256), 0, stream>>>(w4, W);
    k_tail<<<dim3(1), dim3(512), 0, stream>>>(g4, b4, w5, g5, b5, wl, bl, W, out);
}

// Round 13
// 607.555 us; speedup vs baseline: 1.0496x; 1.0496x over previous
//
#include <hip/hip_runtime.h>

#define NPTS 4096
#define KNN 20
#define CNT1f 655360.0f   // B*N*K
#define CNT3f 32768.0f    // B*N
#define BNEPS 1e-5f

// ---- workspace layout (float offsets into d_ws) ----
#define OFF_IDX   0
#define OFF_M     655360     // bf16[32768*128] = 2097152 floats -> ends 2752512
#define OFF_ES    655360     // 32 partials x 32 (27 used)  (alias, pre-c2apply)
#define OFF_G1P   656384     // 4*4096
#define OFF_S1P   672768     // 4*64
#define ZERO1_BEG 655360
#define ZERO1_CNT 17664
#define OFF_W2B   2752512    // bf16[8192]   = 4096 floats
#define OFF_W3B   2756608    // bf16[131072] = 65536 floats -> ends 2822144
#define OFF_XP    2822144    // float4[8*4096] = 131072 floats -> ends 2953216
#define OFF_G3P   2953216    // 2*16384
#define OFF_SM3P  2985984    // 2*128
#define OFF_GMAX  2986240    // 8*1024
#define OFF_Z4    2994432    // 8*512 (no zeroing needed: fc4 full-stores)
#define ZG3_BEG   2953216
#define ZG3_CNT   41216      // G3P + SM3P + GMAX
#define OFF_SC1   4849664
#define OFF_SH1   4849728
#define OFF_SC2   4849792
#define OFF_SH2   4849920
#define OFF_SC3   4850048
#define OFF_SH3   4851072

typedef float f32x4 __attribute__((ext_vector_type(4)));
typedef short s16x8 __attribute__((ext_vector_type(8)));

__device__ __forceinline__ unsigned short f2bf(float f) {   // RNE fp32->bf16
    unsigned u = __float_as_uint(f);
    return (unsigned short)((u + 0x7FFFu + ((u >> 16) & 1u)) >> 16);
}

// zero accum regions + bf16 weight convert + packed float4 point array
__global__ __launch_bounds__(256) void k_initprep(const float* __restrict__ x,
                                                  const float* __restrict__ w2,
                                                  const float* __restrict__ w3, float* W) {
    int i = blockIdx.x * 256 + threadIdx.x;   // grid 512 -> 131072 threads
    unsigned short* w2b = (unsigned short*)(W + OFF_W2B);
    unsigned short* w3b = (unsigned short*)(W + OFF_W3B);
    w3b[i] = f2bf(w3[i]);
    if (i < 8192) w2b[i] = f2bf(w2[i]);
    if (i < ZERO1_CNT) W[ZERO1_BEG + i] = 0.0f;
    if (i < ZG3_CNT) W[ZG3_BEG + i] = 0.0f;
    if (i < 32768) {
        int b = i >> 12, j = i & 4095;
        float4 p;
        p.x = x[b * 12288 + j];
        p.y = x[b * 12288 + 4096 + j];
        p.z = x[b * 12288 + 8192 + j];
        p.w = 0.f;
        ((float4*)(W + OFF_XP))[i] = p;
    }
}

// ---- wave-wide: find bin B containing the K-th smallest (1-indexed) in H ----
template <int PER>
__device__ __forceinline__ void wave_scan_find(const int* H, int K, int lane,
                                               int& B, int& below, int& hB) {
    int c[PER]; int s = 0;
    const int base = lane * PER;
#pragma unroll
    for (int p = 0; p < PER; ++p) { c[p] = H[base + p]; s += c[p]; }
    int pre = s;
#pragma unroll
    for (int off = 1; off < 64; off <<= 1) {
        int t = __shfl_up(pre, off, 64);
        if (lane >= off) pre += t;
    }
    int excl = pre - s;
    bool has = (excl < K) && (K <= excl + s);
    unsigned long long m = __ballot(has);
    int src = (int)(__ffsll((unsigned long long)m) - 1);
    int mb = 0, mbelow = 0, mh = 0;
    if (lane == src) {
        int cum = excl;
#pragma unroll
        for (int p = 0; p < PER; ++p) {
            if (cum < K && K <= cum + c[p]) { mb = base + p; mbelow = cum; mh = c[p]; break; }
            cum += c[p];
        }
    }
    B = __shfl(mb, src, 64);
    below = __shfl(mbelow, src, 64);
    hB = __shfl(mh, src, 64);
}

// -------- KNN radix-select: 2 waves/query (32 keys/lane, VGPR~68, 33% occ)
// + R11-style early exit restored via PREDICATED level skipping: fin flag is
// pair-uniform (both waves scan the same shared histogram), so levels 1/2
// wrap their zero/fill/scan in `if (!fin)` while every __syncthreads stays
// unconditional. R12 measured +35% VALU work from unconditional levels; this
// removes it at unchanged occupancy.
__global__ __launch_bounds__(256) void k_knn(int* __restrict__ idx, float* W) {
    __shared__ int hist[2][512];                     // 4 KB
    __shared__ int outi[2][20];
    __shared__ int cnts[2][2];
    __shared__ unsigned int minsh[2][2];
    __shared__ float estat[27];
    const int tid = threadIdx.x;
    const int b = blockIdx.y;
    const float4* xb4 = ((const float4*)(W + OFF_XP)) + b * NPTS;
    if (tid < 27) estat[tid] = 0.f;
    if (tid < 4) cnts[tid >> 1][tid & 1] = 0;
    const int wv = tid >> 6, lane = tid & 63;
    const int pair = wv >> 1, half = wv & 1;
    const int tid128 = tid & 127;
    const int q = blockIdx.x * 2 + pair;
    const float4 qp = xb4[q];
    int* H = hist[pair];
#pragma unroll
    for (int p = 0; p < 4; ++p) H[tid128 * 4 + p] = 0;
    unsigned int key[32];
    unsigned int mymin = 0xFFFFFFFFu;
#pragma unroll
    for (int it = 0; it < 32; ++it) {
        int j = it * 128 + tid128;
        float4 pp = xb4[j];
        float dx = pp.x - qp.x, dy = pp.y - qp.y, dz = pp.z - qp.z;
        float d = fmaf(dx, dx, fmaf(dy, dy, dz * dz));
        unsigned int u = (j == q) ? 0xFFFFFFFFu : __float_as_uint(d);
        key[it] = u;
        mymin = mymin < u ? mymin : u;
    }
#pragma unroll
    for (int off = 32; off; off >>= 1) {
        unsigned int o = (unsigned int)__shfl_xor((int)mymin, off);
        mymin = mymin < o ? mymin : o;
    }
    if (lane == 0) minsh[pair][half] = mymin;
    __syncthreads();   // minsh + H zero + cnts/estat visible
    const unsigned int base = minsh[pair][0] < minsh[pair][1] ? minsh[pair][0] : minsh[pair][1];
    // ---- level 0: bins (t-base)>>20, clamped ----
#pragma unroll
    for (int it = 0; it < 32; ++it) {
        unsigned int t9 = key[it] - base;
        unsigned int bin = t9 >> 20; if (bin > 511u) bin = 511u;
        atomicAdd(&H[bin], 1);
    }
    __syncthreads();
    int B, below, hB;
    wave_scan_find<8>(H, KNN - 1, lane, B, below, hB);
    unsigned int P = (unsigned int)B;
    int rem = (KNN - 1) - below;
    int S = 20;
    bool fin = (hB == rem);
    __syncthreads();   // scans done reading H
    // ---- level 1 (predicated; barriers unconditional) ----
    if (!fin) {
#pragma unroll
        for (int p = 0; p < 4; ++p) H[tid128 * 4 + p] = 0;
    }
    __syncthreads();
    if (!fin) {
#pragma unroll
        for (int it = 0; it < 32; ++it) {
            unsigned int t9 = key[it] - base;
            unsigned int b0 = t9 >> 20; if (b0 > 511u) b0 = 511u;
            if (b0 == P) atomicAdd(&H[(t9 >> 11) & 511], 1);
        }
    }
    __syncthreads();
    if (!fin) {
        wave_scan_find<8>(H, rem, lane, B, below, hB);
        P = (P << 9) | (unsigned int)B;
        rem -= below;
        S = 11;
        fin = (hB == rem);
    }
    __syncthreads();
    // ---- level 2 (predicated) ----
    if (!fin) {
#pragma unroll
        for (int p = 0; p < 4; ++p) H[tid128 * 4 + p] = 0;
    }
    __syncthreads();
    if (!fin) {
#pragma unroll
        for (int it = 0; it < 32; ++it) {
            unsigned int t9 = key[it] - base;
            if ((t9 >> 11) == P) atomicAdd(&H[(t9 >> 2) & 511], 1);
        }
    }
    __syncthreads();
    if (!fin) {
        wave_scan_find<8>(H, rem, lane, B, below, hB);
        P = (P << 9) | (unsigned int)B;
        rem -= below;
        S = 2;
    }
    // ---- compact: v < P taken; v == P first `rem` taken (19 + self) ----
    int* OC = cnts[pair];
#pragma unroll
    for (int it = 0; it < 32; ++it) {
        unsigned int t9 = key[it] - base;
        unsigned int v;
        if (S == 20) { v = t9 >> 20; if (v > 511u) v = 511u; }
        else v = t9 >> S;
        if (v <= P) {
            bool take = v < P;
            if (!take) { int e = atomicAdd(&OC[1], 1); take = (e < rem); }
            if (take) { int pos = atomicAdd(&OC[0], 1); outi[pair][pos] = it * 128 + tid128; }
        }
    }
    if (half == 0 && lane == 0) outi[pair][KNN - 1] = q;
    __syncthreads();
    const int obase = (b * NPTS + q) * KNN;
    if (half == 0 && lane < KNN) idx[obase + lane] = outi[pair][lane];
    // fused edge moments for bn1 (half==0 wave of each pair, lanes 0..19)
    float st[27];
#pragma unroll
    for (int v = 0; v < 27; ++v) st[v] = 0.f;
    if (half == 0 && lane < KNN) {
        int j = outi[pair][lane];
        float4 np = xb4[j];
        float e[6];
        e[0] = qp.x; e[1] = qp.y; e[2] = qp.z;
        e[3] = np.x - qp.x; e[4] = np.y - qp.y; e[5] = np.z - qp.z;
        int id = 6;
#pragma unroll
        for (int i = 0; i < 6; ++i) {
            st[i] = e[i];
#pragma unroll
            for (int jj = i; jj < 6; ++jj) { st[id] = e[i] * e[jj]; id++; }
        }
    }
    if (half == 0) {
#pragma unroll
        for (int v = 0; v < 27; ++v) {
            float s = st[v];
            s += __shfl_xor(s, 32); s += __shfl_xor(s, 16); s += __shfl_xor(s, 8);
            s += __shfl_xor(s, 4);  s += __shfl_xor(s, 2);  s += __shfl_xor(s, 1);
            st[v] = s;
        }
        if (lane == 0) {
#pragma unroll
            for (int v = 0; v < 27; ++v) atomicAdd(&estat[v], st[v]);
        }
    }
    __syncthreads();
    if (tid < 27) atomicAdd(&W[OFF_ES + (blockIdx.x & 31) * 32 + tid], estat[tid]);
}

// bn1 affine from edge moments
__global__ void k_fin1(const float* __restrict__ w1, const float* __restrict__ g1,
                       const float* __restrict__ b1, float* W) {
    __shared__ float es[27];
    const int c = threadIdx.x;
    if (c < 27) {
        float s = 0.f;
        for (int p = 0; p < 32; ++p) s += W[OFF_ES + p * 32 + c];
        es[c] = s;
    }
    __syncthreads();
    float wr[6];
#pragma unroll
    for (int i = 0; i < 6; ++i) wr[i] = w1[c * 6 + i];
    float m = 0.f;
#pragma unroll
    for (int i = 0; i < 6; ++i) m += wr[i] * es[i];
    m *= (1.f / CNT1f);
    float qv = 0.f;
    int id = 6;
#pragma unroll
    for (int i = 0; i < 6; ++i)
#pragma unroll
        for (int jj = 0; jj < 6; ++jj)
            if (jj >= i) { qv += (jj == i ? 1.f : 2.f) * wr[i] * wr[jj] * es[id]; id++; }
    qv *= (1.f / CNT1f);
    float var = qv - m * m;
    float sc = g1[c] * rsqrtf(var + BNEPS);
    W[OFF_SC1 + c] = sc;
    W[OFF_SH1 + c] = b1[c] - m * sc;
}

// -------- gram1 (MFMA): G1 = Sum(h1 h1^T), S1 via appended ones-row ---------
__global__ __launch_bounds__(256) void k_gram1(const int* __restrict__ idx,
                                               const float* __restrict__ w1, float* W) {
    __shared__ unsigned short h1t[80 * 136];   // 21760 B
    __shared__ float eds[128 * 6];
    __shared__ float w1s[64 * 6];
    __shared__ float sc1s[64], sh1s[64];
    const int t = threadIdx.x;
    const int b = blockIdx.x >> 6;                 // 64 blocks per batch
    const int ebase_b = (blockIdx.x & 63) * 1280;  // edges within batch
    const float4* xpb = ((const float4*)(W + OFF_XP)) + b * NPTS;
    if (t < 384) w1s[t] = w1[t];
    if (t < 64) { sc1s[t] = W[OFF_SC1 + t]; sh1s[t] = W[OFF_SH1 + t]; }
    for (int i = t; i < 2048; i += 256) {          // rows 64..79
        int rr = i >> 7, e = i & 127;
        h1t[(64 + rr) * 136 + e] = (rr == 0) ? (unsigned short)0x3F80 : (unsigned short)0;
    }
    const int w = t >> 6, lane = t & 63, n16 = lane & 15, quad = lane >> 4;
    f32x4 acc[5];
#pragma unroll
    for (int j = 0; j < 5; ++j) acc[j] = (f32x4){0.f, 0.f, 0.f, 0.f};
    for (int ck = 0; ck < 10; ++ck) {
        __syncthreads();
        if (t < 128) {   // stage 128 edges
            int e_l = ebase_b + ck * 128 + t;
            int q = e_l / KNN;
            int jn = idx[b * (NPTS * KNN) + e_l];
            float4 c = xpb[q];
            float4 n = xpb[jn];
            float* E = &eds[t * 6];
            E[0] = c.x; E[1] = c.y; E[2] = c.z;
            E[3] = n.x - c.x; E[4] = n.y - c.y; E[5] = n.z - c.z;
        }
        __syncthreads();
        {   // h1 rows 0..63
            const int e128 = t & 127, half = t >> 7;
            float e0 = eds[e128 * 6 + 0], e1 = eds[e128 * 6 + 1], e2 = eds[e128 * 6 + 2];
            float e3 = eds[e128 * 6 + 3], e4 = eds[e128 * 6 + 4], e5 = eds[e128 * 6 + 5];
#pragma unroll 4
            for (int cc = 0; cc < 32; ++cc) {
                int c = half * 32 + cc;
                const float* wr = &w1s[c * 6];
                float z = wr[0] * e0 + wr[1] * e1 + wr[2] * e2 + wr[3] * e3 + wr[4] * e4 + wr[5] * e5;
                float h = sc1s[c] * z + sh1s[c];
                h1t[c * 136 + e128] = f2bf(h > 0.f ? h : 0.f);
            }
        }
        __syncthreads();
#pragma unroll
        for (int ks = 0; ks < 4; ++ks) {
            s16x8 Af = *(const s16x8*)&h1t[(w * 16 + n16) * 136 + ks * 32 + quad * 8];
#pragma unroll
            for (int jt = 0; jt < 5; ++jt) {
                s16x8 Bf = *(const s16x8*)&h1t[(jt * 16 + n16) * 136 + ks * 32 + quad * 8];
                acc[jt] = __builtin_amdgcn_mfma_f32_16x16x32_bf16(Af, Bf, acc[jt], 0, 0, 0);
            }
        }
    }
    const int part = blockIdx.x & 3;
    const int gi = w * 16 + quad * 4;
#pragma unroll
    for (int jt = 0; jt < 4; ++jt)
#pragma unroll
        for (int r = 0; r < 4; ++r)
            atomicAdd(&W[OFF_G1P + part * 4096 + (gi + r) * 64 + jt * 16 + n16], acc[jt][r]);
    if (n16 == 0) {
#pragma unroll
        for (int r = 0; r < 4; ++r)
            atomicAdd(&W[OFF_S1P + part * 64 + gi + r], acc[4][r]);
    }
}

// bn2 affine from Gram
__global__ __launch_bounds__(256) void k_fin2(const float* __restrict__ w2, const float* __restrict__ g2,
                                              const float* __restrict__ b2, float* W) {
    __shared__ float Gs[4096];
    __shared__ float s1s[64];
    __shared__ float w2s[128 * 65];
    const int t = threadIdx.x;
    for (int i = t; i < 4096; i += 256)
        Gs[i] = W[OFF_G1P + i] + W[OFF_G1P + 4096 + i] + W[OFF_G1P + 8192 + i] + W[OFF_G1P + 12288 + i];
    if (t < 64) s1s[t] = W[OFF_S1P + t] + W[OFF_S1P + 64 + t] + W[OFF_S1P + 128 + t] + W[OFF_S1P + 192 + t];
    for (int i = t; i < 8192; i += 256) w2s[(i >> 6) * 65 + (i & 63)] = w2[i];
    __syncthreads();
    const int c = t >> 1, half = t & 1;
    float acc = 0.f;
    for (int ii = 0; ii < 32; ++ii) {
        int i = 32 * half + ii;
        float wi = w2s[c * 65 + i];
        float inner = 0.f;
        for (int j = 0; j < 64; ++j) inner += Gs[i * 64 + j] * w2s[c * 65 + j];
        acc += wi * inner;
    }
    acc += __shfl_xor(acc, 1);
    if (half == 0) {
        float ms = 0.f;
        for (int j = 0; j < 64; ++j) ms += w2s[c * 65 + j] * s1s[j];
        float mean = ms * (1.f / CNT1f);
        float var = acc * (1.f / CNT1f) - mean * mean;
        float sc = g2[c] * rsqrtf(var + BNEPS);
        W[OFF_SC2 + c] = sc;
        W[OFF_SH2 + c] = b2[c] - mean * sc;
    }
}

// -------- c2apply (MFMA): conv1+bn1+relu -> conv2 -> bn2+relu -> maxK -> M --
__global__ __launch_bounds__(256) void k_c2apply(const int* __restrict__ idx,
                                                 const float* __restrict__ w1, float* W) {
    __shared__ unsigned short h1b[256 * 72];   // [row=q*32+kk][k=64 chans of h1]
    __shared__ float eds[160 * 6];
    const int t = threadIdx.x;
    const int b = blockIdx.y, q0 = blockIdx.x * 8;
    const float4* xpb = ((const float4*)(W + OFF_XP)) + b * NPTS;
    const int ebase = (b * NPTS + q0) * KNN;
    const unsigned short* w2b = (const unsigned short*)(W + OFF_W2B);
    if (t < 160) {
        int q = q0 + t / KNN;
        int jn = idx[ebase + t];
        float4 c = xpb[q];
        float4 n = xpb[jn];
        float* E = &eds[t * 6];
        E[0] = c.x; E[1] = c.y; E[2] = c.z;
        E[3] = n.x - c.x; E[4] = n.y - c.y; E[5] = n.z - c.z;
    }
    __syncthreads();
    {   // h1: thread (chan j64, grp of 2 queries); pad rows 20..31 with zeros
        const int j64 = t & 63, grp = t >> 6;
        float wr[6];
#pragma unroll
        for (int i = 0; i < 6; ++i) wr[i] = w1[j64 * 6 + i];
        const float sc = W[OFF_SC1 + j64], sh = W[OFF_SH1 + j64];
        for (int qq = grp * 2; qq < grp * 2 + 2; ++qq) {
#pragma unroll 4
            for (int kk = 0; kk < 32; ++kk) {
                float v = 0.f;
                if (kk < 20) {
                    const float* E = &eds[(qq * 20 + kk) * 6];
                    float z = wr[0] * E[0] + wr[1] * E[1] + wr[2] * E[2] + wr[3] * E[3] + wr[4] * E[4] + wr[5] * E[5];
                    float h = sc * z + sh;
                    v = h > 0.f ? h : 0.f;
                }
                h1b[(qq * 32 + kk) * 72 + j64] = f2bf(v);
            }
        }
    }
    __syncthreads();
    const int w = t >> 6, lane = t & 63, n16 = lane & 15, quad = lane >> 4;
    unsigned short* Mb = (unsigned short*)(W + OFF_M);
#pragma unroll
    for (int nt_i = 0; nt_i < 2; ++nt_i) {
        const int nt = 2 * w + nt_i;
        const int chan = nt * 16 + n16;
        const float sc2 = W[OFF_SC2 + chan], sh2 = W[OFF_SH2 + chan];
        s16x8 Bf0 = *(const s16x8*)&w2b[chan * 64 + quad * 8];
        s16x8 Bf1 = *(const s16x8*)&w2b[chan * 64 + 32 + quad * 8];
#pragma unroll
        for (int q = 0; q < 8; ++q) {
            f32x4 accA = (f32x4){0.f, 0.f, 0.f, 0.f};
            f32x4 accB = (f32x4){0.f, 0.f, 0.f, 0.f};
            s16x8 a0 = *(const s16x8*)&h1b[(q * 32 + n16) * 72 + quad * 8];
            s16x8 a1 = *(const s16x8*)&h1b[(q * 32 + 16 + n16) * 72 + quad * 8];
            accA = __builtin_amdgcn_mfma_f32_16x16x32_bf16(a0, Bf0, accA, 0, 0, 0);
            accB = __builtin_amdgcn_mfma_f32_16x16x32_bf16(a1, Bf0, accB, 0, 0, 0);
            a0 = *(const s16x8*)&h1b[(q * 32 + n16) * 72 + 32 + quad * 8];
            a1 = *(const s16x8*)&h1b[(q * 32 + 16 + n16) * 72 + 32 + quad * 8];
            accA = __builtin_amdgcn_mfma_f32_16x16x32_bf16(a0, Bf1, accA, 0, 0, 0);
            accB = __builtin_amdgcn_mfma_f32_16x16x32_bf16(a1, Bf1, accB, 0, 0, 0);
            float mx = 0.f;
#pragma unroll
            for (int r = 0; r < 4; ++r) {
                float h = sc2 * accA[r] + sh2;
                mx = fmaxf(mx, h > 0.f ? h : 0.f);
            }
            if (quad == 0) {   // kk = 16..19 valid only in quad 0
#pragma unroll
                for (int r = 0; r < 4; ++r) {
                    float h = sc2 * accB[r] + sh2;
                    mx = fmaxf(mx, h > 0.f ? h : 0.f);
                }
            }
            mx = fmaxf(mx, __shfl_xor(mx, 16));
            mx = fmaxf(mx, __shfl_xor(mx, 32));
            if (quad == 0)
                Mb[(b * NPTS + q0 + q) * 128 + chan] = f2bf(mx);
        }
    }
}

// -------- gram3 (MFMA): G3 = M^T M via transposed bf16 LDS tile -------------
__global__ __launch_bounds__(256) void k_gram3(float* W) {
    __shared__ unsigned short Mt[128 * 72];    // [chan][e], stride 72
    const int t = threadIdx.x;
    const int w = t >> 6, lane = t & 63, n16 = lane & 15, quad = lane >> 4;
    const int r0 = blockIdx.x * 512;
    const unsigned int* Msrc = (const unsigned int*)(W + OFF_M);
    const int nA = 8 - w;
    f32x4 acc[9];
#pragma unroll
    for (int j = 0; j < 9; ++j) acc[j] = (f32x4){0.f, 0.f, 0.f, 0.f};
    float smacc = 0.f;
    for (int ch = 0; ch < 8; ++ch) {
        __syncthreads();
        for (int i = t; i < 4096; i += 256) {   // stage 64 rows transposed
            int row = i >> 6, c2 = i & 63;
            unsigned int v = Msrc[(r0 + ch * 64 + row) * 64 + c2];
            Mt[(2 * c2) * 72 + row]     = (unsigned short)(v & 0xFFFFu);
            Mt[(2 * c2 + 1) * 72 + row] = (unsigned short)(v >> 16);
        }
        __syncthreads();
#pragma unroll
        for (int j = 0; j < 9; ++j) {
            int ti = (j < nA) ? w : (7 - w);
            int tj = (j < nA) ? (w + j) : (j - nA + 7 - w);
#pragma unroll
            for (int ks = 0; ks < 2; ++ks) {
                s16x8 Af = *(const s16x8*)&Mt[(ti * 16 + n16) * 72 + ks * 32 + quad * 8];
                s16x8 Bf = *(const s16x8*)&Mt[(tj * 16 + n16) * 72 + ks * 32 + quad * 8];
                acc[j] = __builtin_amdgcn_mfma_f32_16x16x32_bf16(Af, Bf, acc[j], 0, 0, 0);
            }
        }
        if (t < 128) {
            float s = 0.f;
            for (int e = 0; e < 64; ++e)
                s += __uint_as_float((unsigned int)Mt[t * 72 + e] << 16);
            smacc += s;
        }
    }
    const int part = blockIdx.x & 1;
    float* Gp = &W[OFF_G3P + part * 16384];
#pragma unroll
    for (int j = 0; j < 9; ++j) {
        int ti = (j < nA) ? w : (7 - w);
        int tj = (j < nA) ? (w + j) : (j - nA + 7 - w);
#pragma unroll
        for (int r = 0; r < 4; ++r)
            atomicAdd(&Gp[(ti * 16 + quad * 4 + r) * 128 + tj * 16 + n16], acc[j][r]);
    }
    if (t < 128) atomicAdd(&W[OFF_SM3P + part * 128 + t], smacc);
}

// bn3 affine: 16 channels per block; mirror lower triangle from upper tiles
__global__ __launch_bounds__(256) void k_fin3(const float* __restrict__ w3, const float* __restrict__ g3,
                                              const float* __restrict__ b3, float* W) {
    __shared__ float G3s[128 * 129];
    __shared__ float w3s[16 * 132];
    __shared__ float sm3[128];
    __shared__ float red[256];
    __shared__ float mred[16];
    const int t = threadIdx.x;
    const int c0 = blockIdx.x * 16;
    for (int i = t; i < 16384; i += 256) {
        int row = i >> 7, col = i & 127;
        int src = ((row >> 4) <= (col >> 4)) ? (row * 128 + col) : (col * 128 + row);
        G3s[row * 129 + col] = W[OFF_G3P + src] + W[OFF_G3P + 16384 + src];
    }
    for (int i = t; i < 2048; i += 256)
        w3s[(i >> 7) * 132 + (i & 127)] = w3[(c0 + (i >> 7)) * 128 + (i & 127)];
    if (t < 128) sm3[t] = W[OFF_SM3P + t] + W[OFF_SM3P + 128 + t];
    __syncthreads();
    const int cl = t >> 4, seg = t & 15;
    float acc = 0.f;
    for (int ii = 0; ii < 8; ++ii) {
        int i = 8 * seg + ii;
        float wi = w3s[cl * 132 + i];
        float inner = 0.f;
        for (int j = 0; j < 128; ++j) inner += G3s[i * 129 + j] * w3s[cl * 132 + j];
        acc += wi * inner;
    }
    red[t] = acc;
    if (seg == 0) {
        float ms = 0.f;
        for (int j = 0; j < 128; ++j) ms += w3s[cl * 132 + j] * sm3[j];
        mred[cl] = ms;
    }
    __syncthreads();
    if (t < 16) {
        float s = 0.f;
#pragma unroll
        for (int k = 0; k < 16; ++k) s += red[t * 16 + k];
        float mean = mred[t] * (1.f / CNT3f);
        float var = s * (1.f / CNT3f) - mean * mean;
        float sc = g3[c0 + t] * rsqrtf(var + BNEPS);
        W[OFF_SC3 + c0 + t] = sc;
        W[OFF_SH3 + c0 + t] = b3[c0 + t] - mean * sc;
    }
}

// -------- conv3 (MFMA): z3 = M @ w3^T, bn3+relu, max over rows -> GMAX ------
__global__ __launch_bounds__(256) void k_conv3(float* W) {
    __shared__ unsigned short Mt[64 * 136];     // 64 rows x K=128
    const int t = threadIdx.x;
    const int p0 = blockIdx.x * 64, c0g = blockIdx.y * 128;
    const unsigned int* Msrc = (const unsigned int*)(W + OFF_M);
    const unsigned short* w3b = (const unsigned short*)(W + OFF_W3B);
    for (int i = t; i < 4096; i += 256) {
        int row = i >> 6, c2 = i & 63;
        *(unsigned int*)&Mt[row * 136 + 2 * c2] = Msrc[(p0 + row) * 64 + c2];
    }
    __syncthreads();
    const int w = t >> 6, lane = t & 63, n16 = lane & 15, quad = lane >> 4;
    const int bbatch = p0 >> 12;
#pragma unroll
    for (int nt_i = 0; nt_i < 2; ++nt_i) {
        const int nt = 2 * w + nt_i;
        const int chan = c0g + nt * 16 + n16;
        const float sc3 = W[OFF_SC3 + chan], sh3 = W[OFF_SH3 + chan];
        s16x8 Bf[4];
#pragma unroll
        for (int ks = 0; ks < 4; ++ks)
            Bf[ks] = *(const s16x8*)&w3b[chan * 128 + ks * 32 + quad * 8];
        float mx = 0.f;
#pragma unroll
        for (int mt = 0; mt < 4; ++mt) {
            f32x4 acc = (f32x4){0.f, 0.f, 0.f, 0.f};
#pragma unroll
            for (int ks = 0; ks < 4; ++ks) {
                s16x8 Af = *(const s16x8*)&Mt[(mt * 16 + n16) * 136 + ks * 32 + quad * 8];
                acc = __builtin_amdgcn_mfma_f32_16x16x32_bf16(Af, Bf[ks], acc, 0, 0, 0);
            }
#pragma unroll
            for (int r = 0; r < 4; ++r) {
                float h = sc3 * acc[r] + sh3;
                mx = fmaxf(mx, h > 0.f ? h : 0.f);
            }
        }
        mx = fmaxf(mx, __shfl_xor(mx, 16));
        mx = fmaxf(mx, __shfl_xor(mx, 32));
        if (quad == 0)
            atomicMax((unsigned int*)&W[OFF_GMAX + bbatch * 1024 + chan], __float_as_uint(mx));
    }
}

// -------- z4 = gmax(8x1024) @ w4^T(512x1024) --------------------------------
__global__ __launch_bounds__(256) void k_fc4(const float* __restrict__ w4, float* W) {
    __shared__ float red[256];
    const int t = threadIdx.x;
    const int oidx = t >> 3, s = t & 7;
    const int cc = oidx >> 3, b = oidx & 7;
    const int c = blockIdx.x * 4 + cc;
    const float* g = &W[OFF_GMAX];
    const float* wr = &w4[c * 1024 + s * 128];
    const float* gr = &g[b * 1024 + s * 128];
    float p = 0.f;
    for (int j = 0; j < 128; ++j) p += wr[j] * gr[j];
    red[t] = p;
    __syncthreads();
    if (t < 32) {
        float tot = 0.f;
        for (int k = 0; k < 8; ++k) tot += red[t * 8 + k];
        W[OFF_Z4 + (t & 7) * 512 + blockIdx.x * 4 + (t >> 3)] = tot;
    }
}

// -------- tail: bn4+relu, fc5, bn5+relu, final linear + eye -----------------
__global__ __launch_bounds__(512) void k_tail(const float* __restrict__ g4, const float* __restrict__ b4,
                                              const float* __restrict__ w5, const float* __restrict__ g5,
                                              const float* __restrict__ b5, const float* __restrict__ wl,
                                              const float* __restrict__ bl, float* W, float* __restrict__ out) {
    __shared__ float h4L[8 * 512];
    __shared__ float w5s[2 * 256 * 9];
    __shared__ float zp[2 * 2048];
    const int t = threadIdx.x;
    {
        float v[8]; float s = 0.f, q = 0.f;
#pragma unroll
        for (int b = 0; b < 8; ++b) { v[b] = W[OFF_Z4 + b * 512 + t]; s += v[b]; q += v[b] * v[b]; }
        float mean = s * 0.125f;
        float var = q * 0.125f - mean * mean;
        float sc = g4[t] * rsqrtf(var + BNEPS);
        float sh = b4[t] - mean * sc;
#pragma unroll
        for (int b = 0; b < 8; ++b) {
            float h = sc * v[b] + sh;
            h4L[b * 512 + t] = h > 0.f ? h : 0.f;
        }
    }
    const int c5 = t & 255, half = t >> 8;
    float acc[8];
#pragma unroll
    for (int b = 0; b < 8; ++b) acc[b] = 0.f;
    for (int jt = 0; jt < 32; ++jt) {
        __syncthreads();
        for (int i = t; i < 4096; i += 512) {
            int h = i >> 11, rem = i & 2047;
            int ci = rem >> 3, jj = rem & 7;
            w5s[h * 2304 + ci * 9 + jj] = w5[ci * 512 + h * 256 + jt * 8 + jj];
        }
        __syncthreads();
#pragma unroll
        for (int jj = 0; jj < 8; ++jj) {
            float wv = w5s[half * 2304 + c5 * 9 + jj];
            int jg = half * 256 + jt * 8 + jj;
#pragma unroll
            for (int b = 0; b < 8; ++b) acc[b] += wv * h4L[b * 512 + jg];
        }
    }
#pragma unroll
    for (int b = 0; b < 8; ++b) zp[half * 2048 + b * 256 + c5] = acc[b];
    __syncthreads();
    if (t < 256) {
        float v[8], s = 0.f, q = 0.f;
#pragma unroll
        for (int b = 0; b < 8; ++b) {
            v[b] = zp[b * 256 + t] + zp[2048 + b * 256 + t];
            s += v[b]; q += v[b] * v[b];
        }
        float mean = s * 0.125f, var = q * 0.125f - mean * mean;
        float sc = g5[t] * rsqrtf(var + BNEPS), sh = b5[t] - mean * sc;
#pragma unroll
        for (int b = 0; b < 8; ++b) { float h = sc * v[b] + sh; zp[b * 256 + t] = h > 0.f ? h : 0.f; }
    }
    __syncthreads();
    if (t < 72) {
        int b = t / 9, r = t % 9;
        float a = bl[r] + ((r == 0 || r == 4 || r == 8) ? 1.f : 0.f);
        for (int j = 0; j < 256; ++j) a += wl[r * 256 + j] * zp[b * 256 + j];
        out[b * 9 + r] = a;
    }
}

extern "C" void kernel_launch(void* const* d_in, const int* in_sizes, int n_in,
                              void* d_out, int out_size, void* d_ws, size_t ws_size,
                              hipStream_t stream) {
    const float* x  = (const float*)d_in[0];
    const float* w1 = (const float*)d_in[1];
    const float* g1 = (const float*)d_in[2];
    const float* b1 = (const float*)d_in[3];
    const float* w2 = (const float*)d_in[4];
    const float* g2 = (const float*)d_in[5];
    const float* b2 = (const float*)d_in[6];
    const float* w3 = (const float*)d_in[7];
    const float* g3 = (const float*)d_in[8];
    const float* b3 = (const float*)d_in[9];
    const float* w4 = (const float*)d_in[10];
    const float* g4 = (const float*)d_in[11];
    const float* b4 = (const float*)d_in[12];
    const float* w5 = (const float*)d_in[13];
    const float* g5 = (const float*)d_in[14];
    const float* b5 = (const float*)d_in[15];
    const float* wl = (const float*)d_in[16];
    const float* bl = (const float*)d_in[17];
    float* W = (float*)d_ws;
    int* idx = (int*)d_ws;
    float* out = (float*)d_out;

    k_initprep<<<dim3(512), dim3(256), 0, stream>>>(x, w2, w3, W);
    k_knn<<<dim3(2048, 8), dim3(256), 0, stream>>>(idx, W);
    k_fin1<<<dim3(1), dim3(64), 0, stream>>>(w1, g1, b1, W);
    k_gram1<<<dim3(512), dim3(256), 0, stream>>>(idx, w1, W);
    k_fin2<<<dim3(1), dim3(256), 0, stream>>>(w2, g2, b2, W);
    k_c2apply<<<dim3(512, 8), dim3(256), 0, stream>>>(idx, w1, W);
    k_gram3<<<dim3(64), dim3(256), 0, stream>>>(W);
    k_fin3<<<dim3(64), dim3(256), 0, stream>>>(w3, g3, b3, W);
    k_conv3<<<dim3(512, 8), dim3(256), 0, stream>>>(W);
    k_fc4<<<dim3(128), dim3(256), 0, stream>>>(w4, W);
    k_tail<<<dim3(1), dim3(512), 0, stream>>>(g4, b4, w5, g5, b5, wl, bl, W, out);
}

// Round 14
// 549.569 us; speedup vs baseline: 1.1604x; 1.1055x over previous
//
#include <hip/hip_runtime.h>

#define NPTS 4096
#define KNN 20
#define CNT1f 655360.0f   // B*N*K
#define CNT3f 32768.0f    // B*N
#define BNEPS 1e-5f

// ---- workspace layout (float offsets into d_ws) ----
#define OFF_IDX   0
#define OFF_M     655360     // bf16[32768*128] = 2097152 floats -> ends 2752512
#define OFF_ES    655360     // 32 partials x 32 (27 used)  (alias, pre-c2apply)
#define OFF_G1P   656384     // 4*4096
#define OFF_S1P   672768     // 4*64
#define ZERO1_BEG 655360
#define ZERO1_CNT 17664
#define OFF_W2B   2752512    // bf16[8192]   = 4096 floats
#define OFF_W3B   2756608    // bf16[131072] = 65536 floats -> ends 2822144
#define OFF_XP    2822144    // float4[8*4096] = 131072 floats -> ends 2953216
#define OFF_G3P   2953216    // 2*16384
#define OFF_SM3P  2985984    // 2*128
#define OFF_GMAX  2986240    // 8*1024
#define OFF_Z4    2994432    // 8*512 (no zeroing needed: fc4 full-stores)
#define ZG3_BEG   2953216
#define ZG3_CNT   41216      // G3P + SM3P + GMAX
#define OFF_SC1   4849664
#define OFF_SH1   4849728
#define OFF_SC2   4849792
#define OFF_SH2   4849920
#define OFF_SC3   4850048
#define OFF_SH3   4851072
#define OFF_H4    4852096    // 8*512 relu(bn4(z4))
#define OFF_Z5    4856192    // 8*256

typedef float f32x4 __attribute__((ext_vector_type(4)));
typedef short s16x8 __attribute__((ext_vector_type(8)));

__device__ __forceinline__ unsigned short f2bf(float f) {   // RNE fp32->bf16
    unsigned u = __float_as_uint(f);
    return (unsigned short)((u + 0x7FFFu + ((u >> 16) & 1u)) >> 16);
}

// zero accum regions + bf16 weight convert + packed float4 point array
__global__ __launch_bounds__(256) void k_initprep(const float* __restrict__ x,
                                                  const float* __restrict__ w2,
                                                  const float* __restrict__ w3, float* W) {
    int i = blockIdx.x * 256 + threadIdx.x;   // grid 512 -> 131072 threads
    unsigned short* w2b = (unsigned short*)(W + OFF_W2B);
    unsigned short* w3b = (unsigned short*)(W + OFF_W3B);
    w3b[i] = f2bf(w3[i]);
    if (i < 8192) w2b[i] = f2bf(w2[i]);
    if (i < ZERO1_CNT) W[ZERO1_BEG + i] = 0.0f;
    if (i < ZG3_CNT) W[ZG3_BEG + i] = 0.0f;
    if (i < 32768) {
        int b = i >> 12, j = i & 4095;
        float4 p;
        p.x = x[b * 12288 + j];
        p.y = x[b * 12288 + 4096 + j];
        p.z = x[b * 12288 + 8192 + j];
        p.w = 0.f;
        ((float4*)(W + OFF_XP))[i] = p;
    }
}

// ---- wave-wide: find bin B containing the K-th smallest (1-indexed) in H ----
template <int PER>
__device__ __forceinline__ void wave_scan_find(const int* H, int K, int lane,
                                               int& B, int& below, int& hB) {
    int c[PER]; int s = 0;
    const int base = lane * PER;
#pragma unroll
    for (int p = 0; p < PER; ++p) { c[p] = H[base + p]; s += c[p]; }
    int pre = s;
#pragma unroll
    for (int off = 1; off < 64; off <<= 1) {
        int t = __shfl_up(pre, off, 64);
        if (lane >= off) pre += t;
    }
    int excl = pre - s;
    bool has = (excl < K) && (K <= excl + s);
    unsigned long long m = __ballot(has);
    int src = (int)(__ffsll((unsigned long long)m) - 1);
    int mb = 0, mbelow = 0, mh = 0;
    if (lane == src) {
        int cum = excl;
#pragma unroll
        for (int p = 0; p < PER; ++p) {
            if (cum < K && K <= cum + c[p]) { mb = base + p; mbelow = cum; mh = c[p]; break; }
            cum += c[p];
        }
    }
    B = __shfl(mb, src, 64);
    below = __shfl(mbelow, src, 64);
    hB = __shfl(mh, src, 64);
}

// -------- KNN radix-select: 2 waves/query (32 keys/lane), 1024-bin level 0 --
// Pair structure (R12/R13: low VGPR) + R6/R11's measured-best fine level-0
// binning (1024 bins, shift 19) so most queries finish in one pass. Levels
// 1/2 predicated on the pair-uniform fin flag; barriers unconditional.
__global__ __launch_bounds__(256) void k_knn(int* __restrict__ idx, float* W) {
    __shared__ int hist[2][1024];                    // 8 KB
    __shared__ int outi[2][20];
    __shared__ int cnts[2][2];
    __shared__ unsigned int minsh[2][2];
    __shared__ float estat[27];
    const int tid = threadIdx.x;
    const int b = blockIdx.y;
    const float4* xb4 = ((const float4*)(W + OFF_XP)) + b * NPTS;
    if (tid < 27) estat[tid] = 0.f;
    if (tid < 4) cnts[tid >> 1][tid & 1] = 0;
    const int wv = tid >> 6, lane = tid & 63;
    const int pair = wv >> 1, half = wv & 1;
    const int tid128 = tid & 127;
    const int q = blockIdx.x * 2 + pair;
    const float4 qp = xb4[q];
    int* H = hist[pair];
#pragma unroll
    for (int p = 0; p < 8; ++p) H[tid128 * 8 + p] = 0;
    unsigned int key[32];
    unsigned int mymin = 0xFFFFFFFFu;
#pragma unroll
    for (int it = 0; it < 32; ++it) {
        int j = it * 128 + tid128;
        float4 pp = xb4[j];
        float dx = pp.x - qp.x, dy = pp.y - qp.y, dz = pp.z - qp.z;
        float d = fmaf(dx, dx, fmaf(dy, dy, dz * dz));
        unsigned int u = (j == q) ? 0xFFFFFFFFu : __float_as_uint(d);
        key[it] = u;
        mymin = mymin < u ? mymin : u;
    }
#pragma unroll
    for (int off = 32; off; off >>= 1) {
        unsigned int o = (unsigned int)__shfl_xor((int)mymin, off);
        mymin = mymin < o ? mymin : o;
    }
    if (lane == 0) minsh[pair][half] = mymin;
    __syncthreads();   // minsh + H zero + cnts/estat visible
    const unsigned int base = minsh[pair][0] < minsh[pair][1] ? minsh[pair][0] : minsh[pair][1];
    // ---- level 0: bins (t-base)>>19, clamped to 1023 ----
#pragma unroll
    for (int it = 0; it < 32; ++it) {
        unsigned int t9 = key[it] - base;
        unsigned int bin = t9 >> 19; if (bin > 1023u) bin = 1023u;
        atomicAdd(&H[bin], 1);
    }
    __syncthreads();
    int B, below, hB;
    wave_scan_find<16>(H, KNN - 1, lane, B, below, hB);
    unsigned int P = (unsigned int)B;
    int rem = (KNN - 1) - below;
    int S = 19;
    bool fin = (hB == rem);
    __syncthreads();   // scans done reading H
    // ---- level 1 (predicated; barriers unconditional): bins (t>>10)&511 ----
    if (!fin) {
#pragma unroll
        for (int p = 0; p < 4; ++p) H[tid128 * 4 + p] = 0;
    }
    __syncthreads();
    if (!fin) {
#pragma unroll
        for (int it = 0; it < 32; ++it) {
            unsigned int t9 = key[it] - base;
            unsigned int b0 = t9 >> 19; if (b0 > 1023u) b0 = 1023u;
            if (b0 == P) atomicAdd(&H[(t9 >> 10) & 511], 1);
        }
    }
    __syncthreads();
    if (!fin) {
        wave_scan_find<8>(H, rem, lane, B, below, hB);
        P = (P << 9) | (unsigned int)B;
        rem -= below;
        S = 10;
        fin = (hB == rem);
    }
    __syncthreads();
    // ---- level 2 (predicated): bins (t>>1)&511 ----
    if (!fin) {
#pragma unroll
        for (int p = 0; p < 4; ++p) H[tid128 * 4 + p] = 0;
    }
    __syncthreads();
    if (!fin) {
#pragma unroll
        for (int it = 0; it < 32; ++it) {
            unsigned int t9 = key[it] - base;
            if ((t9 >> 10) == P) atomicAdd(&H[(t9 >> 1) & 511], 1);
        }
    }
    __syncthreads();
    if (!fin) {
        wave_scan_find<8>(H, rem, lane, B, below, hB);
        P = (P << 9) | (unsigned int)B;
        rem -= below;
        S = 1;
    }
    // ---- compact: v < P taken; v == P first `rem` taken (19 + self) ----
    int* OC = cnts[pair];
#pragma unroll
    for (int it = 0; it < 32; ++it) {
        unsigned int t9 = key[it] - base;
        unsigned int v;
        if (S == 19) { v = t9 >> 19; if (v > 1023u) v = 1023u; }
        else v = t9 >> S;
        if (v <= P) {
            bool take = v < P;
            if (!take) { int e = atomicAdd(&OC[1], 1); take = (e < rem); }
            if (take) { int pos = atomicAdd(&OC[0], 1); outi[pair][pos] = it * 128 + tid128; }
        }
    }
    if (half == 0 && lane == 0) outi[pair][KNN - 1] = q;
    __syncthreads();
    const int obase = (b * NPTS + q) * KNN;
    if (half == 0 && lane < KNN) idx[obase + lane] = outi[pair][lane];
    // fused edge moments for bn1 (half==0 wave of each pair, lanes 0..19)
    float st[27];
#pragma unroll
    for (int v = 0; v < 27; ++v) st[v] = 0.f;
    if (half == 0 && lane < KNN) {
        int j = outi[pair][lane];
        float4 np = xb4[j];
        float e[6];
        e[0] = qp.x; e[1] = qp.y; e[2] = qp.z;
        e[3] = np.x - qp.x; e[4] = np.y - qp.y; e[5] = np.z - qp.z;
        int id = 6;
#pragma unroll
        for (int i = 0; i < 6; ++i) {
            st[i] = e[i];
#pragma unroll
            for (int jj = i; jj < 6; ++jj) { st[id] = e[i] * e[jj]; id++; }
        }
    }
    if (half == 0) {
#pragma unroll
        for (int v = 0; v < 27; ++v) {
            float s = st[v];
            s += __shfl_xor(s, 32); s += __shfl_xor(s, 16); s += __shfl_xor(s, 8);
            s += __shfl_xor(s, 4);  s += __shfl_xor(s, 2);  s += __shfl_xor(s, 1);
            st[v] = s;
        }
        if (lane == 0) {
#pragma unroll
            for (int v = 0; v < 27; ++v) atomicAdd(&estat[v], st[v]);
        }
    }
    __syncthreads();
    if (tid < 27) atomicAdd(&W[OFF_ES + (blockIdx.x & 31) * 32 + tid], estat[tid]);
}

// bn1 affine from edge moments
__global__ void k_fin1(const float* __restrict__ w1, const float* __restrict__ g1,
                       const float* __restrict__ b1, float* W) {
    __shared__ float es[27];
    const int c = threadIdx.x;
    if (c < 27) {
        float s = 0.f;
        for (int p = 0; p < 32; ++p) s += W[OFF_ES + p * 32 + c];
        es[c] = s;
    }
    __syncthreads();
    float wr[6];
#pragma unroll
    for (int i = 0; i < 6; ++i) wr[i] = w1[c * 6 + i];
    float m = 0.f;
#pragma unroll
    for (int i = 0; i < 6; ++i) m += wr[i] * es[i];
    m *= (1.f / CNT1f);
    float qv = 0.f;
    int id = 6;
#pragma unroll
    for (int i = 0; i < 6; ++i)
#pragma unroll
        for (int jj = 0; jj < 6; ++jj)
            if (jj >= i) { qv += (jj == i ? 1.f : 2.f) * wr[i] * wr[jj] * es[id]; id++; }
    qv *= (1.f / CNT1f);
    float var = qv - m * m;
    float sc = g1[c] * rsqrtf(var + BNEPS);
    W[OFF_SC1 + c] = sc;
    W[OFF_SH1 + c] = b1[c] - m * sc;
}

// -------- gram1 (MFMA): G1 = Sum(h1 h1^T), S1 via appended ones-row ---------
__global__ __launch_bounds__(256) void k_gram1(const int* __restrict__ idx,
                                               const float* __restrict__ w1, float* W) {
    __shared__ unsigned short h1t[80 * 136];   // 21760 B
    __shared__ float eds[128 * 6];
    __shared__ float w1s[64 * 6];
    __shared__ float sc1s[64], sh1s[64];
    const int t = threadIdx.x;
    const int b = blockIdx.x >> 6;                 // 64 blocks per batch
    const int ebase_b = (blockIdx.x & 63) * 1280;  // edges within batch
    const float4* xpb = ((const float4*)(W + OFF_XP)) + b * NPTS;
    if (t < 384) w1s[t] = w1[t];
    if (t < 64) { sc1s[t] = W[OFF_SC1 + t]; sh1s[t] = W[OFF_SH1 + t]; }
    for (int i = t; i < 2048; i += 256) {          // rows 64..79
        int rr = i >> 7, e = i & 127;
        h1t[(64 + rr) * 136 + e] = (rr == 0) ? (unsigned short)0x3F80 : (unsigned short)0;
    }
    const int w = t >> 6, lane = t & 63, n16 = lane & 15, quad = lane >> 4;
    f32x4 acc[5];
#pragma unroll
    for (int j = 0; j < 5; ++j) acc[j] = (f32x4){0.f, 0.f, 0.f, 0.f};
    for (int ck = 0; ck < 10; ++ck) {
        __syncthreads();
        if (t < 128) {   // stage 128 edges
            int e_l = ebase_b + ck * 128 + t;
            int q = e_l / KNN;
            int jn = idx[b * (NPTS * KNN) + e_l];
            float4 c = xpb[q];
            float4 n = xpb[jn];
            float* E = &eds[t * 6];
            E[0] = c.x; E[1] = c.y; E[2] = c.z;
            E[3] = n.x - c.x; E[4] = n.y - c.y; E[5] = n.z - c.z;
        }
        __syncthreads();
        {   // h1 rows 0..63
            const int e128 = t & 127, half = t >> 7;
            float e0 = eds[e128 * 6 + 0], e1 = eds[e128 * 6 + 1], e2 = eds[e128 * 6 + 2];
            float e3 = eds[e128 * 6 + 3], e4 = eds[e128 * 6 + 4], e5 = eds[e128 * 6 + 5];
#pragma unroll 4
            for (int cc = 0; cc < 32; ++cc) {
                int c = half * 32 + cc;
                const float* wr = &w1s[c * 6];
                float z = wr[0] * e0 + wr[1] * e1 + wr[2] * e2 + wr[3] * e3 + wr[4] * e4 + wr[5] * e5;
                float h = sc1s[c] * z + sh1s[c];
                h1t[c * 136 + e128] = f2bf(h > 0.f ? h : 0.f);
            }
        }
        __syncthreads();
#pragma unroll
        for (int ks = 0; ks < 4; ++ks) {
            s16x8 Af = *(const s16x8*)&h1t[(w * 16 + n16) * 136 + ks * 32 + quad * 8];
#pragma unroll
            for (int jt = 0; jt < 5; ++jt) {
                s16x8 Bf = *(const s16x8*)&h1t[(jt * 16 + n16) * 136 + ks * 32 + quad * 8];
                acc[jt] = __builtin_amdgcn_mfma_f32_16x16x32_bf16(Af, Bf, acc[jt], 0, 0, 0);
            }
        }
    }
    const int part = blockIdx.x & 3;
    const int gi = w * 16 + quad * 4;
#pragma unroll
    for (int jt = 0; jt < 4; ++jt)
#pragma unroll
        for (int r = 0; r < 4; ++r)
            atomicAdd(&W[OFF_G1P + part * 4096 + (gi + r) * 64 + jt * 16 + n16], acc[jt][r]);
    if (n16 == 0) {
#pragma unroll
        for (int r = 0; r < 4; ++r)
            atomicAdd(&W[OFF_S1P + part * 64 + gi + r], acc[4][r]);
    }
}

// bn2 affine from Gram
__global__ __launch_bounds__(256) void k_fin2(const float* __restrict__ w2, const float* __restrict__ g2,
                                              const float* __restrict__ b2, float* W) {
    __shared__ float Gs[4096];
    __shared__ float s1s[64];
    __shared__ float w2s[128 * 65];
    const int t = threadIdx.x;
    for (int i = t; i < 4096; i += 256)
        Gs[i] = W[OFF_G1P + i] + W[OFF_G1P + 4096 + i] + W[OFF_G1P + 8192 + i] + W[OFF_G1P + 12288 + i];
    if (t < 64) s1s[t] = W[OFF_S1P + t] + W[OFF_S1P + 64 + t] + W[OFF_S1P + 128 + t] + W[OFF_S1P + 192 + t];
    for (int i = t; i < 8192; i += 256) w2s[(i >> 6) * 65 + (i & 63)] = w2[i];
    __syncthreads();
    const int c = t >> 1, half = t & 1;
    float acc = 0.f;
    for (int ii = 0; ii < 32; ++ii) {
        int i = 32 * half + ii;
        float wi = w2s[c * 65 + i];
        float inner = 0.f;
        for (int j = 0; j < 64; ++j) inner += Gs[i * 64 + j] * w2s[c * 65 + j];
        acc += wi * inner;
    }
    acc += __shfl_xor(acc, 1);
    if (half == 0) {
        float ms = 0.f;
        for (int j = 0; j < 64; ++j) ms += w2s[c * 65 + j] * s1s[j];
        float mean = ms * (1.f / CNT1f);
        float var = acc * (1.f / CNT1f) - mean * mean;
        float sc = g2[c] * rsqrtf(var + BNEPS);
        W[OFF_SC2 + c] = sc;
        W[OFF_SH2 + c] = b2[c] - mean * sc;
    }
}

// -------- c2apply (MFMA): conv1+bn1+relu -> conv2 -> bn2+relu -> maxK -> M --
__global__ __launch_bounds__(256) void k_c2apply(const int* __restrict__ idx,
                                                 const float* __restrict__ w1, float* W) {
    __shared__ unsigned short h1b[256 * 72];   // [row=q*32+kk][k=64 chans of h1]
    __shared__ float eds[160 * 6];
    const int t = threadIdx.x;
    const int b = blockIdx.y, q0 = blockIdx.x * 8;
    const float4* xpb = ((const float4*)(W + OFF_XP)) + b * NPTS;
    const int ebase = (b * NPTS + q0) * KNN;
    const unsigned short* w2b = (const unsigned short*)(W + OFF_W2B);
    if (t < 160) {
        int q = q0 + t / KNN;
        int jn = idx[ebase + t];
        float4 c = xpb[q];
        float4 n = xpb[jn];
        float* E = &eds[t * 6];
        E[0] = c.x; E[1] = c.y; E[2] = c.z;
        E[3] = n.x - c.x; E[4] = n.y - c.y; E[5] = n.z - c.z;
    }
    __syncthreads();
    {   // h1: thread (chan j64, grp of 2 queries); pad rows 20..31 with zeros
        const int j64 = t & 63, grp = t >> 6;
        float wr[6];
#pragma unroll
        for (int i = 0; i < 6; ++i) wr[i] = w1[j64 * 6 + i];
        const float sc = W[OFF_SC1 + j64], sh = W[OFF_SH1 + j64];
        for (int qq = grp * 2; qq < grp * 2 + 2; ++qq) {
#pragma unroll 4
            for (int kk = 0; kk < 32; ++kk) {
                float v = 0.f;
                if (kk < 20) {
                    const float* E = &eds[(qq * 20 + kk) * 6];
                    float z = wr[0] * E[0] + wr[1] * E[1] + wr[2] * E[2] + wr[3] * E[3] + wr[4] * E[4] + wr[5] * E[5];
                    float h = sc * z + sh;
                    v = h > 0.f ? h : 0.f;
                }
                h1b[(qq * 32 + kk) * 72 + j64] = f2bf(v);
            }
        }
    }
    __syncthreads();
    const int w = t >> 6, lane = t & 63, n16 = lane & 15, quad = lane >> 4;
    unsigned short* Mb = (unsigned short*)(W + OFF_M);
#pragma unroll
    for (int nt_i = 0; nt_i < 2; ++nt_i) {
        const int nt = 2 * w + nt_i;
        const int chan = nt * 16 + n16;
        const float sc2 = W[OFF_SC2 + chan], sh2 = W[OFF_SH2 + chan];
        s16x8 Bf0 = *(const s16x8*)&w2b[chan * 64 + quad * 8];
        s16x8 Bf1 = *(const s16x8*)&w2b[chan * 64 + 32 + quad * 8];
#pragma unroll
        for (int q = 0; q < 8; ++q) {
            f32x4 accA = (f32x4){0.f, 0.f, 0.f, 0.f};
            f32x4 accB = (f32x4){0.f, 0.f, 0.f, 0.f};
            s16x8 a0 = *(const s16x8*)&h1b[(q * 32 + n16) * 72 + quad * 8];
            s16x8 a1 = *(const s16x8*)&h1b[(q * 32 + 16 + n16) * 72 + quad * 8];
            accA = __builtin_amdgcn_mfma_f32_16x16x32_bf16(a0, Bf0, accA, 0, 0, 0);
            accB = __builtin_amdgcn_mfma_f32_16x16x32_bf16(a1, Bf0, accB, 0, 0, 0);
            a0 = *(const s16x8*)&h1b[(q * 32 + n16) * 72 + 32 + quad * 8];
            a1 = *(const s16x8*)&h1b[(q * 32 + 16 + n16) * 72 + 32 + quad * 8];
            accA = __builtin_amdgcn_mfma_f32_16x16x32_bf16(a0, Bf1, accA, 0, 0, 0);
            accB = __builtin_amdgcn_mfma_f32_16x16x32_bf16(a1, Bf1, accB, 0, 0, 0);
            float mx = 0.f;
#pragma unroll
            for (int r = 0; r < 4; ++r) {
                float h = sc2 * accA[r] + sh2;
                mx = fmaxf(mx, h > 0.f ? h : 0.f);
            }
            if (quad == 0) {   // kk = 16..19 valid only in quad 0
#pragma unroll
                for (int r = 0; r < 4; ++r) {
                    float h = sc2 * accB[r] + sh2;
                    mx = fmaxf(mx, h > 0.f ? h : 0.f);
                }
            }
            mx = fmaxf(mx, __shfl_xor(mx, 16));
            mx = fmaxf(mx, __shfl_xor(mx, 32));
            if (quad == 0)
                Mb[(b * NPTS + q0 + q) * 128 + chan] = f2bf(mx);
        }
    }
}

// -------- gram3 (MFMA): G3 = M^T M via transposed bf16 LDS tile -------------
__global__ __launch_bounds__(256) void k_gram3(float* W) {
    __shared__ unsigned short Mt[128 * 72];    // [chan][e], stride 72
    const int t = threadIdx.x;
    const int w = t >> 6, lane = t & 63, n16 = lane & 15, quad = lane >> 4;
    const int r0 = blockIdx.x * 512;
    const unsigned int* Msrc = (const unsigned int*)(W + OFF_M);
    const int nA = 8 - w;
    f32x4 acc[9];
#pragma unroll
    for (int j = 0; j < 9; ++j) acc[j] = (f32x4){0.f, 0.f, 0.f, 0.f};
    float smacc = 0.f;
    for (int ch = 0; ch < 8; ++ch) {
        __syncthreads();
        for (int i = t; i < 4096; i += 256) {   // stage 64 rows transposed
            int row = i >> 6, c2 = i & 63;
            unsigned int v = Msrc[(r0 + ch * 64 + row) * 64 + c2];
            Mt[(2 * c2) * 72 + row]     = (unsigned short)(v & 0xFFFFu);
            Mt[(2 * c2 + 1) * 72 + row] = (unsigned short)(v >> 16);
        }
        __syncthreads();
#pragma unroll
        for (int j = 0; j < 9; ++j) {
            int ti = (j < nA) ? w : (7 - w);
            int tj = (j < nA) ? (w + j) : (j - nA + 7 - w);
#pragma unroll
            for (int ks = 0; ks < 2; ++ks) {
                s16x8 Af = *(const s16x8*)&Mt[(ti * 16 + n16) * 72 + ks * 32 + quad * 8];
                s16x8 Bf = *(const s16x8*)&Mt[(tj * 16 + n16) * 72 + ks * 32 + quad * 8];
                acc[j] = __builtin_amdgcn_mfma_f32_16x16x32_bf16(Af, Bf, acc[j], 0, 0, 0);
            }
        }
        if (t < 128) {
            float s = 0.f;
            for (int e = 0; e < 64; ++e)
                s += __uint_as_float((unsigned int)Mt[t * 72 + e] << 16);
            smacc += s;
        }
    }
    const int part = blockIdx.x & 1;
    float* Gp = &W[OFF_G3P + part * 16384];
#pragma unroll
    for (int j = 0; j < 9; ++j) {
        int ti = (j < nA) ? w : (7 - w);
        int tj = (j < nA) ? (w + j) : (j - nA + 7 - w);
#pragma unroll
        for (int r = 0; r < 4; ++r)
            atomicAdd(&Gp[(ti * 16 + quad * 4 + r) * 128 + tj * 16 + n16], acc[j][r]);
    }
    if (t < 128) atomicAdd(&W[OFF_SM3P + part * 128 + t], smacc);
}

// bn3 affine: 16 channels per block; mirror lower triangle from upper tiles
__global__ __launch_bounds__(256) void k_fin3(const float* __restrict__ w3, const float* __restrict__ g3,
                                              const float* __restrict__ b3, float* W) {
    __shared__ float G3s[128 * 129];
    __shared__ float w3s[16 * 132];
    __shared__ float sm3[128];
    __shared__ float red[256];
    __shared__ float mred[16];
    const int t = threadIdx.x;
    const int c0 = blockIdx.x * 16;
    for (int i = t; i < 16384; i += 256) {
        int row = i >> 7, col = i & 127;
        int src = ((row >> 4) <= (col >> 4)) ? (row * 128 + col) : (col * 128 + row);
        G3s[row * 129 + col] = W[OFF_G3P + src] + W[OFF_G3P + 16384 + src];
    }
    for (int i = t; i < 2048; i += 256)
        w3s[(i >> 7) * 132 + (i & 127)] = w3[(c0 + (i >> 7)) * 128 + (i & 127)];
    if (t < 128) sm3[t] = W[OFF_SM3P + t] + W[OFF_SM3P + 128 + t];
    __syncthreads();
    const int cl = t >> 4, seg = t & 15;
    float acc = 0.f;
    for (int ii = 0; ii < 8; ++ii) {
        int i = 8 * seg + ii;
        float wi = w3s[cl * 132 + i];
        float inner = 0.f;
        for (int j = 0; j < 128; ++j) inner += G3s[i * 129 + j] * w3s[cl * 132 + j];
        acc += wi * inner;
    }
    red[t] = acc;
    if (seg == 0) {
        float ms = 0.f;
        for (int j = 0; j < 128; ++j) ms += w3s[cl * 132 + j] * sm3[j];
        mred[cl] = ms;
    }
    __syncthreads();
    if (t < 16) {
        float s = 0.f;
#pragma unroll
        for (int k = 0; k < 16; ++k) s += red[t * 16 + k];
        float mean = mred[t] * (1.f / CNT3f);
        float var = s * (1.f / CNT3f) - mean * mean;
        float sc = g3[c0 + t] * rsqrtf(var + BNEPS);
        W[OFF_SC3 + c0 + t] = sc;
        W[OFF_SH3 + c0 + t] = b3[c0 + t] - mean * sc;
    }
}

// -------- conv3 (MFMA): z3 = M @ w3^T, bn3+relu, max over rows -> GMAX ------
__global__ __launch_bounds__(256) void k_conv3(float* W) {
    __shared__ unsigned short Mt[64 * 136];     // 64 rows x K=128
    const int t = threadIdx.x;
    const int p0 = blockIdx.x * 64, c0g = blockIdx.y * 128;
    const unsigned int* Msrc = (const unsigned int*)(W + OFF_M);
    const unsigned short* w3b = (const unsigned short*)(W + OFF_W3B);
    for (int i = t; i < 4096; i += 256) {
        int row = i >> 6, c2 = i & 63;
        *(unsigned int*)&Mt[row * 136 + 2 * c2] = Msrc[(p0 + row) * 64 + c2];
    }
    __syncthreads();
    const int w = t >> 6, lane = t & 63, n16 = lane & 15, quad = lane >> 4;
    const int bbatch = p0 >> 12;
#pragma unroll
    for (int nt_i = 0; nt_i < 2; ++nt_i) {
        const int nt = 2 * w + nt_i;
        const int chan = c0g + nt * 16 + n16;
        const float sc3 = W[OFF_SC3 + chan], sh3 = W[OFF_SH3 + chan];
        s16x8 Bf[4];
#pragma unroll
        for (int ks = 0; ks < 4; ++ks)
            Bf[ks] = *(const s16x8*)&w3b[chan * 128 + ks * 32 + quad * 8];
        float mx = 0.f;
#pragma unroll
        for (int mt = 0; mt < 4; ++mt) {
            f32x4 acc = (f32x4){0.f, 0.f, 0.f, 0.f};
#pragma unroll
            for (int ks = 0; ks < 4; ++ks) {
                s16x8 Af = *(const s16x8*)&Mt[(mt * 16 + n16) * 136 + ks * 32 + quad * 8];
                acc = __builtin_amdgcn_mfma_f32_16x16x32_bf16(Af, Bf[ks], acc, 0, 0, 0);
            }
#pragma unroll
            for (int r = 0; r < 4; ++r) {
                float h = sc3 * acc[r] + sh3;
                mx = fmaxf(mx, h > 0.f ? h : 0.f);
            }
        }
        mx = fmaxf(mx, __shfl_xor(mx, 16));
        mx = fmaxf(mx, __shfl_xor(mx, 32));
        if (quad == 0)
            atomicMax((unsigned int*)&W[OFF_GMAX + bbatch * 1024 + chan], __float_as_uint(mx));
    }
}

// -------- z4 = gmax(8x1024) @ w4^T(512x1024) --------------------------------
__global__ __launch_bounds__(256) void k_fc4(const float* __restrict__ w4, float* W) {
    __shared__ float red[256];
    const int t = threadIdx.x;
    const int oidx = t >> 3, s = t & 7;
    const int cc = oidx >> 3, b = oidx & 7;
    const int c = blockIdx.x * 4 + cc;
    const float* g = &W[OFF_GMAX];
    const float* wr = &w4[c * 1024 + s * 128];
    const float* gr = &g[b * 1024 + s * 128];
    float p = 0.f;
    for (int j = 0; j < 128; ++j) p += wr[j] * gr[j];
    red[t] = p;
    __syncthreads();
    if (t < 32) {
        float tot = 0.f;
        for (int k = 0; k < 8; ++k) tot += red[t * 8 + k];
        W[OFF_Z4 + (t & 7) * 512 + blockIdx.x * 4 + (t >> 3)] = tot;
    }
}

// -------- fin4: bn4 stats + relu -> H4 (8x512) ------------------------------
__global__ __launch_bounds__(512) void k_fin4(const float* __restrict__ g4, const float* __restrict__ b4,
                                              float* W) {
    const int t = threadIdx.x;   // 512
    float v[8]; float s = 0.f, q = 0.f;
#pragma unroll
    for (int b = 0; b < 8; ++b) { v[b] = W[OFF_Z4 + b * 512 + t]; s += v[b]; q += v[b] * v[b]; }
    float mean = s * 0.125f;
    float var = q * 0.125f - mean * mean;
    float sc = g4[t] * rsqrtf(var + BNEPS);
    float sh = b4[t] - mean * sc;
#pragma unroll
    for (int b = 0; b < 8; ++b) {
        float h = sc * v[b] + sh;
        W[OFF_H4 + b * 512 + t] = h > 0.f ? h : 0.f;
    }
}

// -------- fc5 (parallel): z5 = H4(8x512) @ w5^T(256x512) --------------------
__global__ __launch_bounds__(256) void k_fc5(const float* __restrict__ w5, float* W) {
    __shared__ float red[256];
    const int t = threadIdx.x;
    const int c4 = t >> 6, b = (t >> 3) & 7, s = t & 7;
    const int c = blockIdx.x * 4 + c4;
    const float* wr = &w5[c * 512 + s * 64];
    const float* hr = &W[OFF_H4 + b * 512 + s * 64];
    float p = 0.f;
    for (int j = 0; j < 64; ++j) p += wr[j] * hr[j];
    red[t] = p;
    __syncthreads();
    if (t < 32) {
        const int cc = t >> 3, bb = t & 7;
        float tot = 0.f;
        for (int k = 0; k < 8; ++k) tot += red[cc * 64 + bb * 8 + k];
        W[OFF_Z5 + bb * 256 + blockIdx.x * 4 + cc] = tot;
    }
}

// -------- tail2: bn5+relu, final linear + eye -------------------------------
__global__ __launch_bounds__(256) void k_tail2(const float* __restrict__ g5, const float* __restrict__ b5,
                                               const float* __restrict__ wl, const float* __restrict__ bl,
                                               float* W, float* __restrict__ out) {
    __shared__ float zp[2048];
    const int t = threadIdx.x;   // 256
    {
        float v[8], s = 0.f, q = 0.f;
#pragma unroll
        for (int b = 0; b < 8; ++b) {
            v[b] = W[OFF_Z5 + b * 256 + t];
            s += v[b]; q += v[b] * v[b];
        }
        float mean = s * 0.125f, var = q * 0.125f - mean * mean;
        float sc = g5[t] * rsqrtf(var + BNEPS), sh = b5[t] - mean * sc;
#pragma unroll
        for (int b = 0; b < 8; ++b) { float h = sc * v[b] + sh; zp[b * 256 + t] = h > 0.f ? h : 0.f; }
    }
    __syncthreads();
    if (t < 72) {
        int b = t / 9, r = t % 9;
        float a = bl[r] + ((r == 0 || r == 4 || r == 8) ? 1.f : 0.f);
        for (int j = 0; j < 256; ++j) a += wl[r * 256 + j] * zp[b * 256 + j];
        out[b * 9 + r] = a;
    }
}

extern "C" void kernel_launch(void* const* d_in, const int* in_sizes, int n_in,
                              void* d_out, int out_size, void* d_ws, size_t ws_size,
                              hipStream_t stream) {
    const float* x  = (const float*)d_in[0];
    const float* w1 = (const float*)d_in[1];
    const float* g1 = (const float*)d_in[2];
    const float* b1 = (const float*)d_in[3];
    const float* w2 = (const float*)d_in[4];
    const float* g2 = (const float*)d_in[5];
    const float* b2 = (const float*)d_in[6];
    const float* w3 = (const float*)d_in[7];
    const float* g3 = (const float*)d_in[8];
    const float* b3 = (const float*)d_in[9];
    const float* w4 = (const float*)d_in[10];
    const float* g4 = (const float*)d_in[11];
    const float* b4 = (const float*)d_in[12];
    const float* w5 = (const float*)d_in[13];
    const float* g5 = (const float*)d_in[14];
    const float* b5 = (const float*)d_in[15];
    const float* wl = (const float*)d_in[16];
    const float* bl = (const float*)d_in[17];
    float* W = (float*)d_ws;
    int* idx = (int*)d_ws;
    float* out = (float*)d_out;

    k_initprep<<<dim3(512), dim3(256), 0, stream>>>(x, w2, w3, W);
    k_knn<<<dim3(2048, 8), dim3(256), 0, stream>>>(idx, W);
    k_fin1<<<dim3(1), dim3(64), 0, stream>>>(w1, g1, b1, W);
    k_gram1<<<dim3(512), dim3(256), 0, stream>>>(idx, w1, W);
    k_fin2<<<dim3(1), dim3(256), 0, stream>>>(w2, g2, b2, W);
    k_c2apply<<<dim3(512, 8), dim3(256), 0, stream>>>(idx, w1, W);
    k_gram3<<<dim3(64), dim3(256), 0, stream>>>(W);
    k_fin3<<<dim3(64), dim3(256), 0, stream>>>(w3, g3, b3, W);
    k_conv3<<<dim3(512, 8), dim3(256), 0, stream>>>(W);
    k_fc4<<<dim3(128), dim3(256), 0, stream>>>(w4, W);
    k_fin4<<<dim3(1), dim3(512), 0, stream>>>(g4, b4, W);
    k_fc5<<<dim3(64), dim3(256), 0, stream>>>(w5, W);
    k_tail2<<<dim3(1), dim3(256), 0, stream>>>(g5, b5, wl, bl, W, out);
}

// Round 15
// 524.130 us; speedup vs baseline: 1.2167x; 1.0485x over previous
//
#include <hip/hip_runtime.h>

#define NPTS 4096
#define KNN 20
#define CNT1f 655360.0f   // B*N*K
#define CNT3f 32768.0f    // B*N
#define BNEPS 1e-5f

// ---- workspace layout (float offsets into d_ws) ----
#define OFF_IDX   0
#define OFF_M     655360     // bf16[32768*128] = 2097152 floats -> ends 2752512
#define OFF_ES    655360     // 32 partials x 32 (27 used)  (alias, pre-c2apply)
#define OFF_G1P   656384     // 4*4096
#define OFF_S1P   672768     // 4*64
#define ZERO1_BEG 655360
#define ZERO1_CNT 17664
#define OFF_W2B   2752512    // bf16[8192]   = 4096 floats
#define OFF_W3B   2756608    // bf16[131072] = 65536 floats -> ends 2822144
#define OFF_XP    2822144    // float4[8*4096] = 131072 floats -> ends 2953216
#define OFF_G3P   2953216    // 2*16384
#define OFF_SM3P  2985984    // 2*128
#define OFF_GMAX  2986240    // 8*1024
#define OFF_Z4    2994432    // 8*512 (no zeroing needed: fc4 full-stores)
#define ZG3_BEG   2953216
#define ZG3_CNT   41216      // G3P + SM3P + GMAX
#define OFF_SC1   4849664
#define OFF_SH1   4849728
#define OFF_SC2   4849792
#define OFF_SH2   4849920
#define OFF_SC3   4850048
#define OFF_SH3   4851072
#define OFF_H4    4852096    // 8*512 relu(bn4(z4))
#define OFF_Z5    4856192    // 8*256 -> ends 4858240
#define OFF_W1B   4858240    // bf16[64*32] = 1024 floats (K padded 6->32)

typedef float f32x4 __attribute__((ext_vector_type(4)));
typedef short s16x8 __attribute__((ext_vector_type(8)));

__device__ __forceinline__ unsigned short f2bf(float f) {   // RNE fp32->bf16
    unsigned u = __float_as_uint(f);
    return (unsigned short)((u + 0x7FFFu + ((u >> 16) & 1u)) >> 16);
}

// zero accum regions + bf16 weight convert (w1 padded to K=32) + packed points
__global__ __launch_bounds__(256) void k_initprep(const float* __restrict__ x,
                                                  const float* __restrict__ w1,
                                                  const float* __restrict__ w2,
                                                  const float* __restrict__ w3, float* W) {
    int i = blockIdx.x * 256 + threadIdx.x;   // grid 512 -> 131072 threads
    unsigned short* w1b = (unsigned short*)(W + OFF_W1B);
    unsigned short* w2b = (unsigned short*)(W + OFF_W2B);
    unsigned short* w3b = (unsigned short*)(W + OFF_W3B);
    w3b[i] = f2bf(w3[i]);
    if (i < 8192) w2b[i] = f2bf(w2[i]);
    if (i < 2048) {
        int c = i >> 5, k = i & 31;
        w1b[i] = (k < 6) ? f2bf(w1[c * 6 + k]) : (unsigned short)0;
    }
    if (i < ZERO1_CNT) W[ZERO1_BEG + i] = 0.0f;
    if (i < ZG3_CNT) W[ZG3_BEG + i] = 0.0f;
    if (i < 32768) {
        int b = i >> 12, j = i & 4095;
        float4 p;
        p.x = x[b * 12288 + j];
        p.y = x[b * 12288 + 4096 + j];
        p.z = x[b * 12288 + 8192 + j];
        p.w = 0.f;
        ((float4*)(W + OFF_XP))[i] = p;
    }
}

// ---- wave-wide: find bin B containing the K-th smallest (1-indexed) in H ----
template <int PER>
__device__ __forceinline__ void wave_scan_find(const int* H, int K, int lane,
                                               int& B, int& below, int& hB) {
    int c[PER]; int s = 0;
    const int base = lane * PER;
#pragma unroll
    for (int p = 0; p < PER; ++p) { c[p] = H[base + p]; s += c[p]; }
    int pre = s;
#pragma unroll
    for (int off = 1; off < 64; off <<= 1) {
        int t = __shfl_up(pre, off, 64);
        if (lane >= off) pre += t;
    }
    int excl = pre - s;
    bool has = (excl < K) && (K <= excl + s);
    unsigned long long m = __ballot(has);
    int src = (int)(__ffsll((unsigned long long)m) - 1);
    int mb = 0, mbelow = 0, mh = 0;
    if (lane == src) {
        int cum = excl;
#pragma unroll
        for (int p = 0; p < PER; ++p) {
            if (cum < K && K <= cum + c[p]) { mb = base + p; mbelow = cum; mh = c[p]; break; }
            cum += c[p];
        }
    }
    B = __shfl(mb, src, 64);
    below = __shfl(mbelow, src, 64);
    hB = __shfl(mh, src, 64);
}

// -------- KNN radix-select: R11 measured-best (solo wave/query, 252 us) -----
__global__ __launch_bounds__(256) void k_knn(int* __restrict__ idx, float* W) {
    __shared__ int hist[4][1024];                    // 16 KB
    __shared__ int outi[4][20];
    __shared__ int cnts[4][2];
    __shared__ float estat[27];
    const int tid = threadIdx.x;
    const int b = blockIdx.y;
    const float4* xb4 = ((const float4*)(W + OFF_XP)) + b * NPTS;
    if (tid < 27) estat[tid] = 0.f;
    if (tid < 8) cnts[tid >> 1][tid & 1] = 0;
    const int wv = tid >> 6, lane = tid & 63;
    const int q = blockIdx.x * 4 + wv;
    const float4 qp = xb4[q];
    int* H = hist[wv];
    unsigned int key[64];
    unsigned int mymin = 0xFFFFFFFFu;
#pragma unroll
    for (int p = 0; p < 16; ++p) H[lane * 16 + p] = 0;
#pragma unroll
    for (int it = 0; it < 64; ++it) {
        int j = it * 64 + lane;
        float4 pp = xb4[j];
        float dx = pp.x - qp.x, dy = pp.y - qp.y, dz = pp.z - qp.z;
        float d = fmaf(dx, dx, fmaf(dy, dy, dz * dz));
        unsigned int u = (j == q) ? 0xFFFFFFFFu : __float_as_uint(d);
        key[it] = u;
        mymin = mymin < u ? mymin : u;
    }
    __syncthreads();   // cnts/estat init visible block-wide
#pragma unroll
    for (int off = 32; off; off >>= 1) {
        unsigned int o = (unsigned int)__shfl_xor((int)mymin, off);
        mymin = mymin < o ? mymin : o;
    }
    const unsigned int base = mymin;
#pragma unroll
    for (int it = 0; it < 64; ++it) {
        unsigned int t9 = key[it] - base;
        unsigned int bin = t9 >> 19; if (bin > 1023u) bin = 1023u;
        atomicAdd(&H[bin], 1);
    }
    int B, below, hB;
    wave_scan_find<16>(H, KNN - 1, lane, B, below, hB);
    unsigned int P = (unsigned int)B;
    int rem = (KNN - 1) - below;
    int S = 19;
    if (hB != rem) {
#pragma unroll
        for (int p = 0; p < 8; ++p) H[lane * 8 + p] = 0;
#pragma unroll
        for (int it = 0; it < 64; ++it) {
            unsigned int t9 = key[it] - base;
            unsigned int b0 = t9 >> 19; if (b0 > 1023u) b0 = 1023u;
            if (b0 == P) atomicAdd(&H[(t9 >> 10) & 511], 1);
        }
        wave_scan_find<8>(H, rem, lane, B, below, hB);
        P = (P << 9) | (unsigned int)B;
        rem -= below;
        S = 10;
        if (hB != rem) {
#pragma unroll
            for (int p = 0; p < 8; ++p) H[lane * 8 + p] = 0;
#pragma unroll
            for (int it = 0; it < 64; ++it) {
                unsigned int t9 = key[it] - base;
                if ((t9 >> 10) == P) atomicAdd(&H[(t9 >> 1) & 511], 1);
            }
            wave_scan_find<8>(H, rem, lane, B, below, hB);
            P = (P << 9) | (unsigned int)B;
            rem -= below;
            S = 1;
        }
    }
    // compact: v < P always taken; v == P first `rem` taken (19 total + self)
    int* OC = cnts[wv];
#pragma unroll
    for (int it = 0; it < 64; ++it) {
        unsigned int t9 = key[it] - base;
        unsigned int v;
        if (S == 19) { v = t9 >> 19; if (v > 1023u) v = 1023u; }
        else v = t9 >> S;
        if (v <= P) {
            bool take = v < P;
            if (!take) { int e = atomicAdd(&OC[1], 1); take = (e < rem); }
            if (take) { int pos = atomicAdd(&OC[0], 1); outi[wv][pos] = it * 64 + lane; }
        }
    }
    if (lane == 0) outi[wv][KNN - 1] = q;
    const int obase = (b * NPTS + q) * KNN;
    if (lane < KNN) idx[obase + lane] = outi[wv][lane];
    // fused edge moments for bn1
    float st[27];
#pragma unroll
    for (int v = 0; v < 27; ++v) st[v] = 0.f;
    if (lane < KNN) {
        int j = outi[wv][lane];
        float4 np = xb4[j];
        float e[6];
        e[0] = qp.x; e[1] = qp.y; e[2] = qp.z;
        e[3] = np.x - qp.x; e[4] = np.y - qp.y; e[5] = np.z - qp.z;
        int id = 6;
#pragma unroll
        for (int i = 0; i < 6; ++i) {
            st[i] = e[i];
#pragma unroll
            for (int jj = i; jj < 6; ++jj) { st[id] = e[i] * e[jj]; id++; }
        }
    }
#pragma unroll
    for (int v = 0; v < 27; ++v) {
        float s = st[v];
        s += __shfl_xor(s, 32); s += __shfl_xor(s, 16); s += __shfl_xor(s, 8);
        s += __shfl_xor(s, 4);  s += __shfl_xor(s, 2);  s += __shfl_xor(s, 1);
        st[v] = s;
    }
    if (lane == 0) {
#pragma unroll
        for (int v = 0; v < 27; ++v) atomicAdd(&estat[v], st[v]);
    }
    __syncthreads();
    if (tid < 27) atomicAdd(&W[OFF_ES + (blockIdx.x & 31) * 32 + tid], estat[tid]);
}

// bn1 affine from edge moments
__global__ void k_fin1(const float* __restrict__ w1, const float* __restrict__ g1,
                       const float* __restrict__ b1, float* W) {
    __shared__ float es[27];
    const int c = threadIdx.x;
    if (c < 27) {
        float s = 0.f;
        for (int p = 0; p < 32; ++p) s += W[OFF_ES + p * 32 + c];
        es[c] = s;
    }
    __syncthreads();
    float wr[6];
#pragma unroll
    for (int i = 0; i < 6; ++i) wr[i] = w1[c * 6 + i];
    float m = 0.f;
#pragma unroll
    for (int i = 0; i < 6; ++i) m += wr[i] * es[i];
    m *= (1.f / CNT1f);
    float qv = 0.f;
    int id = 6;
#pragma unroll
    for (int i = 0; i < 6; ++i)
#pragma unroll
        for (int jj = 0; jj < 6; ++jj)
            if (jj >= i) { qv += (jj == i ? 1.f : 2.f) * wr[i] * wr[jj] * es[id]; id++; }
    qv *= (1.f / CNT1f);
    float var = qv - m * m;
    float sc = g1[c] * rsqrtf(var + BNEPS);
    W[OFF_SC1 + c] = sc;
    W[OFF_SH1 + c] = b1[c] - m * sc;
}

// -------- gram1 (MFMA): conv1 via MFMA (K=6 padded 32) + G1 = Sum(h1 h1^T) --
// Edges staged as bf16 A-fragments; h1 = relu(bn1(eda @ w1b^T)) computed by
// matrix core, epilogue writes transposed [chan][edge] for the Gram MFMAs.
__global__ __launch_bounds__(256) void k_gram1(const int* __restrict__ idx, float* W) {
    __shared__ unsigned short h1t[80 * 136];   // 21760 B: [chan][e]; row64=ones
    __shared__ unsigned short eda[128 * 32];   // 8 KB: A-layout edges, k>=6 zero
    __shared__ float sc1s[64], sh1s[64];
    const int t = threadIdx.x;
    const int b = blockIdx.x >> 6;
    const int ebase_b = (blockIdx.x & 63) * 1280;
    const float4* xpb = ((const float4*)(W + OFF_XP)) + b * NPTS;
    const unsigned short* w1b = (const unsigned short*)(W + OFF_W1B);
    if (t < 64) { sc1s[t] = W[OFF_SC1 + t]; sh1s[t] = W[OFF_SH1 + t]; }
    for (int i = t; i < 2048; i += 256) {   // rows 64..79
        int rr = i >> 7, e = i & 127;
        h1t[(64 + rr) * 136 + e] = (rr == 0) ? (unsigned short)0x3F80 : (unsigned short)0;
    }
    const int w = t >> 6, lane = t & 63, n16 = lane & 15, quad = lane >> 4;
    s16x8 Bw1[4];
#pragma unroll
    for (int nt = 0; nt < 4; ++nt)
        Bw1[nt] = *(const s16x8*)&w1b[(nt * 16 + n16) * 32 + quad * 8];
    f32x4 acc[5];
#pragma unroll
    for (int j = 0; j < 5; ++j) acc[j] = (f32x4){0.f, 0.f, 0.f, 0.f};
    for (int ck = 0; ck < 10; ++ck) {
        __syncthreads();
        if (t < 128) {   // stage 128 edges in A-fragment layout
            int e_l = ebase_b + ck * 128 + t;
            int q = e_l / KNN;
            int jn = idx[b * (NPTS * KNN) + e_l];
            float4 c = xpb[q];
            float4 n = xpb[jn];
            float E[6];
            E[0] = c.x; E[1] = c.y; E[2] = c.z;
            E[3] = n.x - c.x; E[4] = n.y - c.y; E[5] = n.z - c.z;
            unsigned short* row = &eda[t * 32];
#pragma unroll
            for (int k = 0; k < 6; ++k) row[k] = f2bf(E[k]);
#pragma unroll
            for (int k = 6; k < 32; ++k) row[k] = 0;
        }
        __syncthreads();
        // conv1 MFMA: 8 tiles of 16 edges, wave w does tt = w, w+4
#pragma unroll
        for (int i2 = 0; i2 < 2; ++i2) {
            int tt = w + 4 * i2;
            s16x8 Af = *(const s16x8*)&eda[(tt * 16 + n16) * 32 + quad * 8];
#pragma unroll
            for (int nt = 0; nt < 4; ++nt) {
                f32x4 z = (f32x4){0.f, 0.f, 0.f, 0.f};
                z = __builtin_amdgcn_mfma_f32_16x16x32_bf16(Af, Bw1[nt], z, 0, 0, 0);
                int chan = nt * 16 + n16;
                float sc = sc1s[chan], sh = sh1s[chan];
#pragma unroll
                for (int r = 0; r < 4; ++r) {
                    float h = sc * z[r] + sh;
                    h1t[chan * 136 + tt * 16 + quad * 4 + r] = f2bf(h > 0.f ? h : 0.f);
                }
            }
        }
        __syncthreads();
#pragma unroll
        for (int ks = 0; ks < 4; ++ks) {
            s16x8 Af = *(const s16x8*)&h1t[(w * 16 + n16) * 136 + ks * 32 + quad * 8];
#pragma unroll
            for (int jt = 0; jt < 5; ++jt) {
                s16x8 Bf = *(const s16x8*)&h1t[(jt * 16 + n16) * 136 + ks * 32 + quad * 8];
                acc[jt] = __builtin_amdgcn_mfma_f32_16x16x32_bf16(Af, Bf, acc[jt], 0, 0, 0);
            }
        }
    }
    const int part = blockIdx.x & 3;
    const int gi = w * 16 + quad * 4;
#pragma unroll
    for (int jt = 0; jt < 4; ++jt)
#pragma unroll
        for (int r = 0; r < 4; ++r)
            atomicAdd(&W[OFF_G1P + part * 4096 + (gi + r) * 64 + jt * 16 + n16], acc[jt][r]);
    if (n16 == 0) {
#pragma unroll
        for (int r = 0; r < 4; ++r)
            atomicAdd(&W[OFF_S1P + part * 64 + gi + r], acc[4][r]);
    }
}

// bn2 affine from Gram
__global__ __launch_bounds__(256) void k_fin2(const float* __restrict__ w2, const float* __restrict__ g2,
                                              const float* __restrict__ b2, float* W) {
    __shared__ float Gs[4096];
    __shared__ float s1s[64];
    __shared__ float w2s[128 * 65];
    const int t = threadIdx.x;
    for (int i = t; i < 4096; i += 256)
        Gs[i] = W[OFF_G1P + i] + W[OFF_G1P + 4096 + i] + W[OFF_G1P + 8192 + i] + W[OFF_G1P + 12288 + i];
    if (t < 64) s1s[t] = W[OFF_S1P + t] + W[OFF_S1P + 64 + t] + W[OFF_S1P + 128 + t] + W[OFF_S1P + 192 + t];
    for (int i = t; i < 8192; i += 256) w2s[(i >> 6) * 65 + (i & 63)] = w2[i];
    __syncthreads();
    const int c = t >> 1, half = t & 1;
    float acc = 0.f;
    for (int ii = 0; ii < 32; ++ii) {
        int i = 32 * half + ii;
        float wi = w2s[c * 65 + i];
        float inner = 0.f;
        for (int j = 0; j < 64; ++j) inner += Gs[i * 64 + j] * w2s[c * 65 + j];
        acc += wi * inner;
    }
    acc += __shfl_xor(acc, 1);
    if (half == 0) {
        float ms = 0.f;
        for (int j = 0; j < 64; ++j) ms += w2s[c * 65 + j] * s1s[j];
        float mean = ms * (1.f / CNT1f);
        float var = acc * (1.f / CNT1f) - mean * mean;
        float sc = g2[c] * rsqrtf(var + BNEPS);
        W[OFF_SC2 + c] = sc;
        W[OFF_SH2 + c] = b2[c] - mean * sc;
    }
}

// -------- c2apply: conv1 (MFMA, K=6 pad 32) -> conv2 (MFMA) -> bn2+relu
// -> maxK -> M. Pad rows (kk>=20) carry relu(sh1) garbage but only surface in
// discarded accumulator rows (accB quads 1..3) — verified against phase C.
__global__ __launch_bounds__(256) void k_c2apply(const int* __restrict__ idx, float* W) {
    __shared__ unsigned short h1b[256 * 72];   // 36864 B: [row=q*32+kk][chan]
    __shared__ unsigned short eda[160 * 32];   // 10240 B: A-layout edges
    __shared__ float sc1s[64], sh1s[64];
    const int t = threadIdx.x;
    const int b = blockIdx.y, q0 = blockIdx.x * 8;
    const float4* xpb = ((const float4*)(W + OFF_XP)) + b * NPTS;
    const int ebase = (b * NPTS + q0) * KNN;
    const unsigned short* w2b = (const unsigned short*)(W + OFF_W2B);
    const unsigned short* w1b = (const unsigned short*)(W + OFF_W1B);
    if (t < 64) { sc1s[t] = W[OFF_SC1 + t]; sh1s[t] = W[OFF_SH1 + t]; }
    if (t < 160) {
        int q = q0 + t / KNN;
        int jn = idx[ebase + t];
        float4 c = xpb[q];
        float4 n = xpb[jn];
        float E[6];
        E[0] = c.x; E[1] = c.y; E[2] = c.z;
        E[3] = n.x - c.x; E[4] = n.y - c.y; E[5] = n.z - c.z;
        unsigned short* row = &eda[t * 32];
#pragma unroll
        for (int k = 0; k < 6; ++k) row[k] = f2bf(E[k]);
#pragma unroll
        for (int k = 6; k < 32; ++k) row[k] = 0;
    }
    const int w = t >> 6, lane = t & 63, n16 = lane & 15, quad = lane >> 4;
    s16x8 Bw1[4];
#pragma unroll
    for (int nt = 0; nt < 4; ++nt)
        Bw1[nt] = *(const s16x8*)&w1b[(nt * 16 + n16) * 32 + quad * 8];
    __syncthreads();
    // conv1 MFMA: 16 tiles of 16 rows (256 = 8q x 32); wave w: tt = w + 4*i
#pragma unroll
    for (int i2 = 0; i2 < 4; ++i2) {
        int tt = w + 4 * i2;
        int row = tt * 16 + n16;
        int q = row >> 5, kk = row & 31;
        s16x8 Af = (s16x8){0, 0, 0, 0, 0, 0, 0, 0};
        if (kk < 20) Af = *(const s16x8*)&eda[(q * 20 + kk) * 32 + quad * 8];
#pragma unroll
        for (int nt = 0; nt < 4; ++nt) {
            f32x4 z = (f32x4){0.f, 0.f, 0.f, 0.f};
            z = __builtin_amdgcn_mfma_f32_16x16x32_bf16(Af, Bw1[nt], z, 0, 0, 0);
            int chan = nt * 16 + n16;
            float sc = sc1s[chan], sh = sh1s[chan];
#pragma unroll
            for (int r = 0; r < 4; ++r) {
                float h = sc * z[r] + sh;
                h1b[(tt * 16 + quad * 4 + r) * 72 + chan] = f2bf(h > 0.f ? h : 0.f);
            }
        }
    }
    __syncthreads();
    unsigned short* Mb = (unsigned short*)(W + OFF_M);
#pragma unroll
    for (int nt_i = 0; nt_i < 2; ++nt_i) {
        const int nt = 2 * w + nt_i;
        const int chan = nt * 16 + n16;
        const float sc2 = W[OFF_SC2 + chan], sh2 = W[OFF_SH2 + chan];
        s16x8 Bf0 = *(const s16x8*)&w2b[chan * 64 + quad * 8];
        s16x8 Bf1 = *(const s16x8*)&w2b[chan * 64 + 32 + quad * 8];
#pragma unroll
        for (int q = 0; q < 8; ++q) {
            f32x4 accA = (f32x4){0.f, 0.f, 0.f, 0.f};
            f32x4 accB = (f32x4){0.f, 0.f, 0.f, 0.f};
            s16x8 a0 = *(const s16x8*)&h1b[(q * 32 + n16) * 72 + quad * 8];
            s16x8 a1 = *(const s16x8*)&h1b[(q * 32 + 16 + n16) * 72 + quad * 8];
            accA = __builtin_amdgcn_mfma_f32_16x16x32_bf16(a0, Bf0, accA, 0, 0, 0);
            accB = __builtin_amdgcn_mfma_f32_16x16x32_bf16(a1, Bf0, accB, 0, 0, 0);
            a0 = *(const s16x8*)&h1b[(q * 32 + n16) * 72 + 32 + quad * 8];
            a1 = *(const s16x8*)&h1b[(q * 32 + 16 + n16) * 72 + 32 + quad * 8];
            accA = __builtin_amdgcn_mfma_f32_16x16x32_bf16(a0, Bf1, accA, 0, 0, 0);
            accB = __builtin_amdgcn_mfma_f32_16x16x32_bf16(a1, Bf1, accB, 0, 0, 0);
            float mx = 0.f;
#pragma unroll
            for (int r = 0; r < 4; ++r) {
                float h = sc2 * accA[r] + sh2;
                mx = fmaxf(mx, h > 0.f ? h : 0.f);
            }
            if (quad == 0) {   // kk = 16..19 valid only in quad 0
#pragma unroll
                for (int r = 0; r < 4; ++r) {
                    float h = sc2 * accB[r] + sh2;
                    mx = fmaxf(mx, h > 0.f ? h : 0.f);
                }
            }
            mx = fmaxf(mx, __shfl_xor(mx, 16));
            mx = fmaxf(mx, __shfl_xor(mx, 32));
            if (quad == 0)
                Mb[(b * NPTS + q0 + q) * 128 + chan] = f2bf(mx);
        }
    }
}

// -------- gram3 (MFMA): G3 = M^T M via transposed bf16 LDS tile -------------
__global__ __launch_bounds__(256) void k_gram3(float* W) {
    __shared__ unsigned short Mt[128 * 72];    // [chan][e], stride 72
    const int t = threadIdx.x;
    const int w = t >> 6, lane = t & 63, n16 = lane & 15, quad = lane >> 4;
    const int r0 = blockIdx.x * 512;
    const unsigned int* Msrc = (const unsigned int*)(W + OFF_M);
    const int nA = 8 - w;
    f32x4 acc[9];
#pragma unroll
    for (int j = 0; j < 9; ++j) acc[j] = (f32x4){0.f, 0.f, 0.f, 0.f};
    float smacc = 0.f;
    for (int ch = 0; ch < 8; ++ch) {
        __syncthreads();
        for (int i = t; i < 4096; i += 256) {   // stage 64 rows transposed
            int row = i >> 6, c2 = i & 63;
            unsigned int v = Msrc[(r0 + ch * 64 + row) * 64 + c2];
            Mt[(2 * c2) * 72 + row]     = (unsigned short)(v & 0xFFFFu);
            Mt[(2 * c2 + 1) * 72 + row] = (unsigned short)(v >> 16);
        }
        __syncthreads();
#pragma unroll
        for (int j = 0; j < 9; ++j) {
            int ti = (j < nA) ? w : (7 - w);
            int tj = (j < nA) ? (w + j) : (j - nA + 7 - w);
#pragma unroll
            for (int ks = 0; ks < 2; ++ks) {
                s16x8 Af = *(const s16x8*)&Mt[(ti * 16 + n16) * 72 + ks * 32 + quad * 8];
                s16x8 Bf = *(const s16x8*)&Mt[(tj * 16 + n16) * 72 + ks * 32 + quad * 8];
                acc[j] = __builtin_amdgcn_mfma_f32_16x16x32_bf16(Af, Bf, acc[j], 0, 0, 0);
            }
        }
        if (t < 128) {
            float s = 0.f;
            for (int e = 0; e < 64; ++e)
                s += __uint_as_float((unsigned int)Mt[t * 72 + e] << 16);
            smacc += s;
        }
    }
    const int part = blockIdx.x & 1;
    float* Gp = &W[OFF_G3P + part * 16384];
#pragma unroll
    for (int j = 0; j < 9; ++j) {
        int ti = (j < nA) ? w : (7 - w);
        int tj = (j < nA) ? (w + j) : (j - nA + 7 - w);
#pragma unroll
        for (int r = 0; r < 4; ++r)
            atomicAdd(&Gp[(ti * 16 + quad * 4 + r) * 128 + tj * 16 + n16], acc[j][r]);
    }
    if (t < 128) atomicAdd(&W[OFF_SM3P + part * 128 + t], smacc);
}

// bn3 affine: 16 channels per block; mirror lower triangle from upper tiles
__global__ __launch_bounds__(256) void k_fin3(const float* __restrict__ w3, const float* __restrict__ g3,
                                              const float* __restrict__ b3, float* W) {
    __shared__ float G3s[128 * 129];
    __shared__ float w3s[16 * 132];
    __shared__ float sm3[128];
    __shared__ float red[256];
    __shared__ float mred[16];
    const int t = threadIdx.x;
    const int c0 = blockIdx.x * 16;
    for (int i = t; i < 16384; i += 256) {
        int row = i >> 7, col = i & 127;
        int src = ((row >> 4) <= (col >> 4)) ? (row * 128 + col) : (col * 128 + row);
        G3s[row * 129 + col] = W[OFF_G3P + src] + W[OFF_G3P + 16384 + src];
    }
    for (int i = t; i < 2048; i += 256)
        w3s[(i >> 7) * 132 + (i & 127)] = w3[(c0 + (i >> 7)) * 128 + (i & 127)];
    if (t < 128) sm3[t] = W[OFF_SM3P + t] + W[OFF_SM3P + 128 + t];
    __syncthreads();
    const int cl = t >> 4, seg = t & 15;
    float acc = 0.f;
    for (int ii = 0; ii < 8; ++ii) {
        int i = 8 * seg + ii;
        float wi = w3s[cl * 132 + i];
        float inner = 0.f;
        for (int j = 0; j < 128; ++j) inner += G3s[i * 129 + j] * w3s[cl * 132 + j];
        acc += wi * inner;
    }
    red[t] = acc;
    if (seg == 0) {
        float ms = 0.f;
        for (int j = 0; j < 128; ++j) ms += w3s[cl * 132 + j] * sm3[j];
        mred[cl] = ms;
    }
    __syncthreads();
    if (t < 16) {
        float s = 0.f;
#pragma unroll
        for (int k = 0; k < 16; ++k) s += red[t * 16 + k];
        float mean = mred[t] * (1.f / CNT3f);
        float var = s * (1.f / CNT3f) - mean * mean;
        float sc = g3[c0 + t] * rsqrtf(var + BNEPS);
        W[OFF_SC3 + c0 + t] = sc;
        W[OFF_SH3 + c0 + t] = b3[c0 + t] - mean * sc;
    }
}

// -------- conv3 (MFMA): z3 = M @ w3^T, bn3+relu, max over rows -> GMAX ------
__global__ __launch_bounds__(256) void k_conv3(float* W) {
    __shared__ unsigned short Mt[64 * 136];     // 64 rows x K=128
    const int t = threadIdx.x;
    const int p0 = blockIdx.x * 64, c0g = blockIdx.y * 128;
    const unsigned int* Msrc = (const unsigned int*)(W + OFF_M);
    const unsigned short* w3b = (const unsigned short*)(W + OFF_W3B);
    for (int i = t; i < 4096; i += 256) {
        int row = i >> 6, c2 = i & 63;
        *(unsigned int*)&Mt[row * 136 + 2 * c2] = Msrc[(p0 + row) * 64 + c2];
    }
    __syncthreads();
    const int w = t >> 6, lane = t & 63, n16 = lane & 15, quad = lane >> 4;
    const int bbatch = p0 >> 12;
#pragma unroll
    for (int nt_i = 0; nt_i < 2; ++nt_i) {
        const int nt = 2 * w + nt_i;
        const int chan = c0g + nt * 16 + n16;
        const float sc3 = W[OFF_SC3 + chan], sh3 = W[OFF_SH3 + chan];
        s16x8 Bf[4];
#pragma unroll
        for (int ks = 0; ks < 4; ++ks)
            Bf[ks] = *(const s16x8*)&w3b[chan * 128 + ks * 32 + quad * 8];
        float mx = 0.f;
#pragma unroll
        for (int mt = 0; mt < 4; ++mt) {
            f32x4 acc = (f32x4){0.f, 0.f, 0.f, 0.f};
#pragma unroll
            for (int ks = 0; ks < 4; ++ks) {
                s16x8 Af = *(const s16x8*)&Mt[(mt * 16 + n16) * 136 + ks * 32 + quad * 8];
                acc = __builtin_amdgcn_mfma_f32_16x16x32_bf16(Af, Bf[ks], acc, 0, 0, 0);
            }
#pragma unroll
            for (int r = 0; r < 4; ++r) {
                float h = sc3 * acc[r] + sh3;
                mx = fmaxf(mx, h > 0.f ? h : 0.f);
            }
        }
        mx = fmaxf(mx, __shfl_xor(mx, 16));
        mx = fmaxf(mx, __shfl_xor(mx, 32));
        if (quad == 0)
            atomicMax((unsigned int*)&W[OFF_GMAX + bbatch * 1024 + chan], __float_as_uint(mx));
    }
}

// -------- z4 = gmax(8x1024) @ w4^T(512x1024) --------------------------------
__global__ __launch_bounds__(256) void k_fc4(const float* __restrict__ w4, float* W) {
    __shared__ float red[256];
    const int t = threadIdx.x;
    const int oidx = t >> 3, s = t & 7;
    const int cc = oidx >> 3, b = oidx & 7;
    const int c = blockIdx.x * 4 + cc;
    const float* g = &W[OFF_GMAX];
    const float* wr = &w4[c * 1024 + s * 128];
    const float* gr = &g[b * 1024 + s * 128];
    float p = 0.f;
    for (int j = 0; j < 128; ++j) p += wr[j] * gr[j];
    red[t] = p;
    __syncthreads();
    if (t < 32) {
        float tot = 0.f;
        for (int k = 0; k < 8; ++k) tot += red[t * 8 + k];
        W[OFF_Z4 + (t & 7) * 512 + blockIdx.x * 4 + (t >> 3)] = tot;
    }
}

// -------- fin4: bn4 stats + relu -> H4 (8x512) ------------------------------
__global__ __launch_bounds__(512) void k_fin4(const float* __restrict__ g4, const float* __restrict__ b4,
                                              float* W) {
    const int t = threadIdx.x;   // 512
    float v[8]; float s = 0.f, q = 0.f;
#pragma unroll
    for (int b = 0; b < 8; ++b) { v[b] = W[OFF_Z4 + b * 512 + t]; s += v[b]; q += v[b] * v[b]; }
    float mean = s * 0.125f;
    float var = q * 0.125f - mean * mean;
    float sc = g4[t] * rsqrtf(var + BNEPS);
    float sh = b4[t] - mean * sc;
#pragma unroll
    for (int b = 0; b < 8; ++b) {
        float h = sc * v[b] + sh;
        W[OFF_H4 + b * 512 + t] = h > 0.f ? h : 0.f;
    }
}

// -------- fc5 (parallel): z5 = H4(8x512) @ w5^T(256x512) --------------------
__global__ __launch_bounds__(256) void k_fc5(const float* __restrict__ w5, float* W) {
    __shared__ float red[256];
    const int t = threadIdx.x;
    const int c4 = t >> 6, b = (t >> 3) & 7, s = t & 7;
    const int c = blockIdx.x * 4 + c4;
    const float* wr = &w5[c * 512 + s * 64];
    const float* hr = &W[OFF_H4 + b * 512 + s * 64];
    float p = 0.f;
    for (int j = 0; j < 64; ++j) p += wr[j] * hr[j];
    red[t] = p;
    __syncthreads();
    if (t < 32) {
        const int cc = t >> 3, bb = t & 7;
        float tot = 0.f;
        for (int k = 0; k < 8; ++k) tot += red[cc * 64 + bb * 8 + k];
        W[OFF_Z5 + bb * 256 + blockIdx.x * 4 + cc] = tot;
    }
}

// -------- tail2: bn5+relu, final linear + eye -------------------------------
__global__ __launch_bounds__(256) void k_tail2(const float* __restrict__ g5, const float* __restrict__ b5,
                                               const float* __restrict__ wl, const float* __restrict__ bl,
                                               float* W, float* __restrict__ out) {
    __shared__ float zp[2048];
    const int t = threadIdx.x;   // 256
    {
        float v[8], s = 0.f, q = 0.f;
#pragma unroll
        for (int b = 0; b < 8; ++b) {
            v[b] = W[OFF_Z5 + b * 256 + t];
            s += v[b]; q += v[b] * v[b];
        }
        float mean = s * 0.125f, var = q * 0.125f - mean * mean;
        float sc = g5[t] * rsqrtf(var + BNEPS), sh = b5[t] - mean * sc;
#pragma unroll
        for (int b = 0; b < 8; ++b) { float h = sc * v[b] + sh; zp[b * 256 + t] = h > 0.f ? h : 0.f; }
    }
    __syncthreads();
    if (t < 72) {
        int b = t / 9, r = t % 9;
        float a = bl[r] + ((r == 0 || r == 4 || r == 8) ? 1.f : 0.f);
        for (int j = 0; j < 256; ++j) a += wl[r * 256 + j] * zp[b * 256 + j];
        out[b * 9 + r] = a;
    }
}

extern "C" void kernel_launch(void* const* d_in, const int* in_sizes, int n_in,
                              void* d_out, int out_size, void* d_ws, size_t ws_size,
                              hipStream_t stream) {
    const float* x  = (const float*)d_in[0];
    const float* w1 = (const float*)d_in[1];
    const float* g1 = (const float*)d_in[2];
    const float* b1 = (const float*)d_in[3];
    const float* w2 = (const float*)d_in[4];
    const float* g2 = (const float*)d_in[5];
    const float* b2 = (const float*)d_in[6];
    const float* w3 = (const float*)d_in[7];
    const float* g3 = (const float*)d_in[8];
    const float* b3 = (const float*)d_in[9];
    const float* w4 = (const float*)d_in[10];
    const float* g4 = (const float*)d_in[11];
    const float* b4 = (const float*)d_in[12];
    const float* w5 = (const float*)d_in[13];
    const float* g5 = (const float*)d_in[14];
    const float* b5 = (const float*)d_in[15];
    const float* wl = (const float*)d_in[16];
    const float* bl = (const float*)d_in[17];
    float* W = (float*)d_ws;
    int* idx = (int*)d_ws;
    float* out = (float*)d_out;

    k_initprep<<<dim3(512), dim3(256), 0, stream>>>(x, w1, w2, w3, W);
    k_knn<<<dim3(1024, 8), dim3(256), 0, stream>>>(idx, W);
    k_fin1<<<dim3(1), dim3(64), 0, stream>>>(w1, g1, b1, W);
    k_gram1<<<dim3(512), dim3(256), 0, stream>>>(idx, W);
    k_fin2<<<dim3(1), dim3(256), 0, stream>>>(w2, g2, b2, W);
    k_c2apply<<<dim3(512, 8), dim3(256), 0, stream>>>(idx, W);
    k_gram3<<<dim3(64), dim3(256), 0, stream>>>(W);
    k_fin3<<<dim3(64), dim3(256), 0, stream>>>(w3, g3, b3, W);
    k_conv3<<<dim3(512, 8), dim3(256), 0, stream>>>(W);
    k_fc4<<<dim3(128), dim3(256), 0, stream>>>(w4, W);
    k_fin4<<<dim3(1), dim3(512), 0, stream>>>(g4, b4, W);
    k_fc5<<<dim3(64), dim3(256), 0, stream>>>(w5, W);
    k_tail2<<<dim3(1), dim3(256), 0, stream>>>(g5, b5, wl, bl, W, out);
}